// Round 15
// baseline (251.524 us; speedup 1.0000x reference)
//
#include <hip/hip_runtime.h>
#include <hip/hip_bf16.h>

constexpr int D  = 128;
constexpr int H  = 8;
constexpr int DH = 16;
constexpr int NB  = 16;  // nodes per MFMA tile / type-bucket alignment
constexpr int NBO = 8;   // nodes per k_out tile
constexpr int T  = 3;

typedef __attribute__((ext_vector_type(8))) short bf16x8;
typedef __attribute__((ext_vector_type(4))) float f32x4;

__device__ inline unsigned short f2bf(float f) {  // fp32 -> bf16 bits (RNE)
  unsigned u = __float_as_uint(f);
  unsigned r = u + 0x7fffu + ((u >> 16) & 1u);
  return (unsigned short)(r >> 16);
}

// ---------- FiLM: gb[0:128]=gamma, gb[128:256]=beta ----------
__global__ void k_film(const float* __restrict__ gc, const float* __restrict__ fw,
                       const float* __restrict__ fb, float* __restrict__ gb, int C) {
  int j = threadIdx.x;  // 256 threads
  float acc = fb[j];
  for (int c = 0; c < C; ++c) acc += gc[c] * fw[c * 256 + j];
  gb[j] = acc;
}

// ---------- cast x -> bf16 (8 elems/thread) ----------
__global__ void k_cast_x(const float* __restrict__ x, unsigned short* __restrict__ xb,
                         int n8) {
  int i = blockIdx.x * blockDim.x + threadIdx.x;
  if (i >= n8) return;
  const float4* p = (const float4*)(x + (size_t)i * 8);
  float4 a = p[0], b = p[1];
  ushort4 o0 = {f2bf(a.x), f2bf(a.y), f2bf(a.z), f2bf(a.w)};
  ushort4 o1 = {f2bf(b.x), f2bf(b.y), f2bf(b.z), f2bf(b.w)};
  ushort4* q = (ushort4*)(xb + (size_t)i * 8);
  q[0] = o0;
  q[1] = o1;
}

// ---------- weight prep: blocks 0-8: Wk/Wq/Wv -> bf16 Wt[m][t][col][k];
//            blocks 9-11: Wa -> fp32 transposed WaT[t][col][k] ----------
__global__ void k_cast_w(const float* __restrict__ Wk, const float* __restrict__ Wq,
                         const float* __restrict__ Wv, const float* __restrict__ Wa,
                         unsigned short* __restrict__ Wt, float* __restrict__ WaT) {
  int b = blockIdx.x;  // 12 blocks
  if (b < 9) {
    int m = b / T, t = b % T;
    const float* W = (m == 0 ? Wk : m == 1 ? Wq : Wv) + (size_t)t * (D * D);
    unsigned short* o = Wt + ((size_t)m * T + t) * (D * D);
    for (int idx = threadIdx.x; idx < D * D; idx += blockDim.x) {
      int d = idx >> 7, c = idx & 127;          // read coalesced in c
      o[(size_t)c * D + d] = f2bf(W[idx]);      // transposed write
    }
  } else {
    int t = b - 9;
    const float* W = Wa + (size_t)t * (D * D);
    float* o = WaT + (size_t)t * (D * D);
    for (int idx = threadIdx.x; idx < D * D; idx += blockDim.x) {
      int d = idx >> 7, c = idx & 127;
      o[(size_t)c * D + d] = W[idx];            // fp32 transposed copy
    }
  }
}

// ---------- count in-degree + type histogram (wave-aggregated) ----------
__global__ void k_count(const int* __restrict__ dst, const int* __restrict__ ntype,
                        int* __restrict__ deg, int* __restrict__ tcnt, int N, int E) {
  int i = blockIdx.x * blockDim.x + threadIdx.x;
  if (i < E) atomicAdd(deg + dst[i], 1);
  int t = (i < N) ? ntype[i] : -1;
  int lane = threadIdx.x & 63;
#pragma unroll
  for (int tt = 0; tt < T; ++tt) {
    unsigned long long mask = __ballot(t == tt);
    int cnt = __popcll(mask);
    if (cnt > 0 && lane == (__ffsll((long long)mask) - 1))
      atomicAdd(tcnt + tt, cnt);
  }
}

// ---------- exclusive prefix sum over deg -> off[0..N]; also toff from tcnt ----------
__global__ void k_scan(const int* __restrict__ deg, int* __restrict__ off,
                       const int* __restrict__ tcnt, int* __restrict__ toff,
                       int N, int E) {
  __shared__ int wsum[16];
  __shared__ int base_s;
  int tid = threadIdx.x;          // 0..1023
  int lane = tid & 63, w = tid >> 6;
  if (tid == 0) {
    base_s = 0;
    toff[0] = 0;
    for (int t = 0; t < T; ++t) toff[t + 1] = toff[t] + ((tcnt[t] + NB - 1) / NB) * NB;
  }
  __syncthreads();
  for (int start = 0; start < N; start += 1024) {
    int i = start + tid;
    int v = (i < N) ? deg[i] : 0;
    int x = v;
#pragma unroll
    for (int o = 1; o < 64; o <<= 1) {
      int y = __shfl_up(x, o);
      if (lane >= o) x += y;
    }
    if (lane == 63) wsum[w] = x;
    __syncthreads();
    if (w == 0 && lane < 16) {
      int s = wsum[lane];
#pragma unroll
      for (int o = 1; o < 16; o <<= 1) {
        int y = __shfl_up(s, o);
        if (lane >= o) s += y;
      }
      wsum[lane] = s;
    }
    __syncthreads();
    int waveoff = (w > 0) ? wsum[w - 1] : 0;
    if (i < N) off[i] = base_s + waveoff + x - v;
    __syncthreads();
    if (tid == 0) base_s += wsum[15];
    __syncthreads();
  }
  if (tid == 0) off[N] = E;
}

// ---------- scatter: edges -> CSR src values; nodes -> type buckets ----------
__global__ void k_scatter(const int* __restrict__ dst, const int* __restrict__ src,
                          const int* __restrict__ ntype,
                          const int* __restrict__ off, const int* __restrict__ toff,
                          int* __restrict__ cursor, int* __restrict__ tcur,
                          int* __restrict__ esrc, int* __restrict__ pnid, int N, int E) {
  int i = blockIdx.x * blockDim.x + threadIdx.x;
  if (i < E) {
    int d = dst[i];
    int pos = atomicAdd(cursor + d, 1);
    esrc[off[d] + pos] = src[i];
  }
  int t = (i < N) ? ntype[i] : -1;
  int lane = threadIdx.x & 63;
#pragma unroll
  for (int tt = 0; tt < T; ++tt) {
    unsigned long long mask = __ballot(t == tt);
    int cnt = __popcll(mask);
    if (cnt == 0) continue;
    int leader = __ffsll((long long)mask) - 1;
    int base = 0;
    if (lane == leader) base = atomicAdd(tcur + tt, cnt);
    base = __shfl(base, leader);
    if (t == tt) {
      int rank = __popcll(mask & ((1ull << lane) - 1ull));
      pnid[toff[tt] + base + rank] = i;
    }
  }
}

// ---------- MFMA typed projection: 16 nodes x 128 out, bf16 in, fp32 acc.
//            blockIdx.y: 0=k, 1=q(->qt), 2=v(->mt). 256 thr = 4 waves, each
//            wave owns 32 output cols (2 col-tiles of 16).
//            A-frag: lane l elem i = A[l&15][(l>>4)*8+i]  (row-major)
//            B-frag: lane l elem i = B[(l>>4)*8+i][l&15]  (Wt col-major [c][k])
//            D: col = lane&15, row = (lane>>4)*4+reg  [verified r10/r14] ----------
__global__ void __launch_bounds__(256)
k_proj_m(const unsigned short* __restrict__ xb, const int* __restrict__ pnid,
         const int* __restrict__ ntype, const unsigned short* __restrict__ Wt,
         const float* __restrict__ ra_, const float* __restrict__ rm_,
         const float* __restrict__ rp,
         unsigned int* __restrict__ kmpk, float* __restrict__ oqt) {
  int b = blockIdx.x, which = blockIdx.y;
  int tid = threadIdx.x;
  int w = tid >> 6, l = tid & 63;
  __shared__ int nid_s[NB];
  if (tid < NB) nid_s[tid] = pnid[b * NB + tid];
  __syncthreads();
  int tfirst = -1;
#pragma unroll
  for (int nn = 0; nn < NB; ++nn) if (tfirst < 0 && nid_s[nn] >= 0) tfirst = ntype[nid_s[nn]];
  if (tfirst < 0) return;  // fully-padded block

  int arow = l & 15, kg = l >> 4;
  int anid = nid_s[arow];
  if (anid < 0) anid = 0;  // clamp: garbage rows never written back
  const unsigned short* abase = xb + (size_t)anid * D + kg * 8;
  const unsigned short* wbase = Wt + ((size_t)which * T + tfirst) * (D * D);
  int col0 = w * 32 + (l & 15);
  const unsigned short* b0 = wbase + (size_t)col0 * D + kg * 8;
  const unsigned short* b1 = b0 + (size_t)16 * D;
  f32x4 acc0 = {0.f, 0.f, 0.f, 0.f}, acc1 = {0.f, 0.f, 0.f, 0.f};
#pragma unroll
  for (int ks = 0; ks < 4; ++ks) {
    bf16x8 af = *(const bf16x8*)(abase + ks * 32);
    bf16x8 bf0 = *(const bf16x8*)(b0 + ks * 32);
    bf16x8 bf1 = *(const bf16x8*)(b1 + ks * 32);
    acc0 = __builtin_amdgcn_mfma_f32_16x16x32_bf16(af, bf0, acc0, 0, 0, 0);
    acc1 = __builtin_amdgcn_mfma_f32_16x16x32_bf16(af, bf1, acc1, 0, 0, 0);
  }

  int o = l & 15, kg4 = (l >> 4) * 4, gbase = l & 48;
  unsigned short* kb = (unsigned short*)kmpk;
  if (which == 0) {  // k -> low bf16 half
#pragma unroll
    for (int ct = 0; ct < 2; ++ct) {
      f32x4 acc = ct ? acc1 : acc0;
      int col = w * 32 + ct * 16 + o;
#pragma unroll
      for (int r = 0; r < 4; ++r) {
        int nid = nid_s[kg4 + r];
        if (nid >= 0) kb[((size_t)nid * D + col) * 2] = f2bf(acc[r]);
      }
    }
  } else if (which == 1) {  // q -> qt (rel_att transform + rel_pri/4 scale)
#pragma unroll
    for (int ct = 0; ct < 2; ++ct) {
      f32x4 acc = ct ? acc1 : acc0;
      int h = 2 * w + ct;
      int col = h * 16 + o;
      float raz[16];
#pragma unroll
      for (int z = 0; z < 16; ++z) raz[z] = ra_[h * 256 + o * 16 + z];
      float rph = rp[h] * 0.25f;
#pragma unroll
      for (int r = 0; r < 4; ++r) {
        float s = 0.f;
#pragma unroll
        for (int z = 0; z < 16; ++z) s += raz[z] * __shfl(acc[r], gbase | z);
        int nid = nid_s[kg4 + r];
        if (nid >= 0) oqt[(size_t)nid * D + col] = s * rph;
      }
    }
  } else {  // v -> mt (rel_msg transform) -> high bf16 half
#pragma unroll
    for (int ct = 0; ct < 2; ++ct) {
      f32x4 acc = ct ? acc1 : acc0;
      int h = 2 * w + ct;
      int col = h * 16 + o;
      float rmz[16];
#pragma unroll
      for (int z = 0; z < 16; ++z) rmz[z] = rm_[h * 256 + z * 16 + o];
#pragma unroll
      for (int r = 0; r < 4; ++r) {
        float s = 0.f;
#pragma unroll
        for (int z = 0; z < 16; ++z) s += rmz[z] * __shfl(acc[r], gbase | z);
        int nid = nid_s[kg4 + r];
        if (nid >= 0) kb[((size_t)nid * D + col) * 2 + 1] = f2bf(s);
      }
    }
  }
}

// ---------- per-node online-softmax aggregation (4-way unrolled) -> fp32 hagg ----------
__global__ void k_agg(const int* __restrict__ esrc, const int* __restrict__ off,
                      const unsigned int* __restrict__ kmpk,
                      const float* __restrict__ qt,
                      float* __restrict__ hagg, int N) {
  int n = blockIdx.x;
  int j = threadIdx.x;  // 0..127
  float qv = qt[(size_t)n * D + j];
  int i0 = off[n], i1 = off[n + 1];
  float m = -INFINITY, ssum = 0.f, acc = 0.f;
  int i = i0;
  for (; i + 4 <= i1; i += 4) {
    int s0 = esrc[i], s1 = esrc[i + 1], s2 = esrc[i + 2], s3 = esrc[i + 3];
    unsigned p0 = kmpk[(size_t)s0 * D + j];
    unsigned p1 = kmpk[(size_t)s1 * D + j];
    unsigned p2 = kmpk[(size_t)s2 * D + j];
    unsigned p3 = kmpk[(size_t)s3 * D + j];
    float kv0 = __uint_as_float(p0 << 16), mv0 = __uint_as_float(p0 & 0xffff0000u);
    float kv1 = __uint_as_float(p1 << 16), mv1 = __uint_as_float(p1 & 0xffff0000u);
    float kv2 = __uint_as_float(p2 << 16), mv2 = __uint_as_float(p2 & 0xffff0000u);
    float kv3 = __uint_as_float(p3 << 16), mv3 = __uint_as_float(p3 & 0xffff0000u);
    float a0 = kv0 * qv, a1 = kv1 * qv, a2 = kv2 * qv, a3 = kv3 * qv;
#pragma unroll
    for (int o = 8; o >= 1; o >>= 1) {
      a0 += __shfl_xor(a0, o);
      a1 += __shfl_xor(a1, o);
      a2 += __shfl_xor(a2, o);
      a3 += __shfl_xor(a3, o);
    }
    float mn = fmaxf(fmaxf(m, fmaxf(a0, a1)), fmaxf(a2, a3));
    float sc = __expf(m - mn);
    float w0 = __expf(a0 - mn), w1 = __expf(a1 - mn);
    float w2 = __expf(a2 - mn), w3 = __expf(a3 - mn);
    ssum = ssum * sc + (w0 + w1) + (w2 + w3);
    acc = acc * sc + (w0 * mv0 + w1 * mv1) + (w2 * mv2 + w3 * mv3);
    m = mn;
  }
  for (; i < i1; ++i) {
    int sn = esrc[i];
    unsigned p = kmpk[(size_t)sn * D + j];
    float kv = __uint_as_float(p << 16), mv = __uint_as_float(p & 0xffff0000u);
    float a = kv * qv;
#pragma unroll
    for (int o = 8; o >= 1; o >>= 1) a += __shfl_xor(a, o);
    float mn = fmaxf(m, a);
    float sc = __expf(m - mn);
    float wgt = __expf(a - mn);
    ssum = ssum * sc + wgt;
    acc = acc * sc + wgt * mv;
    m = mn;
  }
  hagg[(size_t)n * D + j] = (ssum > 0.f) ? acc / ssum : 0.f;
}

// ---------- fp32 Wa GEMM (transposed weights, float4) + skip/LN/residual/FiLM ----------
__global__ void __launch_bounds__(128)
k_out(const float* __restrict__ hagg, const int* __restrict__ pnid,
      const int* __restrict__ ntype, const float* __restrict__ WaT,
      const float* __restrict__ x, const float* __restrict__ skip,
      const float* __restrict__ ln_g, const float* __restrict__ ln_b,
      const float* __restrict__ gb, float* __restrict__ out) {
  int b = blockIdx.x, j = threadIdx.x;  // 128 threads
  __shared__ __align__(16) float hs[NBO][D];
  __shared__ int nid_s[NBO];
  __shared__ float red[2][NBO][2];
  if (j < NBO) nid_s[j] = pnid[b * NBO + j];
  __syncthreads();
  for (int idx = j; idx < NBO * D; idx += 128) {
    int nn = idx >> 7, col = idx & 127;
    int nid = nid_s[nn];
    hs[nn][col] = (nid >= 0) ? hagg[(size_t)nid * D + col] : 0.f;
  }
  __syncthreads();
  int tfirst = -1;
#pragma unroll
  for (int nn = 0; nn < NBO; ++nn) if (tfirst < 0 && nid_s[nn] >= 0) tfirst = ntype[nid_s[nn]];
  if (tfirst < 0) return;
  const float* wp = WaT + (size_t)tfirst * (D * D) + (size_t)j * D;  // contiguous in k
  float acc[NBO];
#pragma unroll
  for (int nn = 0; nn < NBO; ++nn) acc[nn] = 0.f;
#pragma unroll 4
  for (int d = 0; d < D; d += 4) {
    float4 wv = *(const float4*)(wp + d);
#pragma unroll
    for (int nn = 0; nn < NBO; ++nn) {
      float4 h4 = *(const float4*)(&hs[nn][d]);
      acc[nn] = fmaf(h4.x, wv.x, acc[nn]);
      acc[nn] = fmaf(h4.y, wv.y, acc[nn]);
      acc[nn] = fmaf(h4.z, wv.z, acc[nn]);
      acc[nn] = fmaf(h4.w, wv.w, acc[nn]);
    }
  }
  float alpha = 1.f / (1.f + __expf(-skip[tfirst]));
  int w = j >> 6;
  float hv[NBO];
#pragma unroll
  for (int nn = 0; nn < NBO; ++nn) {
    int nid = nid_s[nn];
    float xv = (nid >= 0) ? x[(size_t)nid * D + j] : 0.f;
    hv[nn] = (nid >= 0) ? (acc[nn] * alpha + xv * (1.f - alpha)) : 0.f;
    float s1 = hv[nn], s2 = hv[nn] * hv[nn];
#pragma unroll
    for (int o = 1; o < 64; o <<= 1) {
      s1 += __shfl_xor(s1, o);
      s2 += __shfl_xor(s2, o);
    }
    if ((j & 63) == 0) { red[w][nn][0] = s1; red[w][nn][1] = s2; }
  }
  __syncthreads();
  float gj = ln_g[j], bj = ln_b[j], gmj = gb[j], gbj = gb[D + j];
#pragma unroll
  for (int nn = 0; nn < NBO; ++nn) {
    int nid = nid_s[nn];
    if (nid < 0) continue;
    float mu = (red[0][nn][0] + red[1][nn][0]) * (1.f / D);
    float m2 = (red[0][nn][1] + red[1][nn][1]) * (1.f / D);
    float var = m2 - mu * mu;
    float xv = x[(size_t)nid * D + j];
    float y = (hv[nn] - mu) * rsqrtf(var + 1e-5f) * gj + bj + xv;
    out[(size_t)nid * D + j] = gmj * y + gbj;
  }
}

extern "C" void kernel_launch(void* const* d_in, const int* in_sizes, int n_in,
                              void* d_out, int out_size, void* d_ws, size_t ws_size,
                              hipStream_t stream) {
  const float* x       = (const float*)d_in[0];
  const float* gc      = (const float*)d_in[1];
  const float* Wk      = (const float*)d_in[2];
  const float* Wq      = (const float*)d_in[3];
  const float* Wv      = (const float*)d_in[4];
  const float* rel_att = (const float*)d_in[5];
  const float* rel_msg = (const float*)d_in[6];
  const float* rel_pri = (const float*)d_in[7];
  const float* Wa      = (const float*)d_in[8];
  const float* skip    = (const float*)d_in[9];
  const float* ln_g    = (const float*)d_in[10];
  const float* ln_b    = (const float*)d_in[11];
  const float* fw      = (const float*)d_in[12];
  const float* fb      = (const float*)d_in[13];
  const int* ntype     = (const int*)d_in[14];
  const int* src       = (const int*)d_in[15];
  const int* dst       = (const int*)d_in[16];
  float* out = (float*)d_out;

  int N = in_sizes[0] / D;
  int C = in_sizes[1];
  int E = in_sizes[15];

  int gridP = (N + NB - 1) / NB + T;  // upper bound on padded 16-node tiles
  int P = gridP * NB;                 // padded node-list size
  int gridO = P / NBO;                // 8-node tiles

  float* ws = (float*)d_ws;
  size_t nD = (size_t)N * D;
  float* wqt   = ws;                                 // N*128 fp32 qt (scaled)
  float* whagg = wqt + nD;                           // N*128 fp32 h_agg
  float* wgb   = whagg + nD;                         // 256 gamma|beta
  unsigned int*   kmpk = (unsigned int*)(wgb + 256); // N*128 packed {k,mt} bf16
  unsigned short* xb   = (unsigned short*)(kmpk + nD);  // N*128 bf16 x
  unsigned short* Wt   = xb + nD;                    // 3*3*128*128 bf16 col-major
  float* WaT  = (float*)(Wt + 9 * D * D);            // 3*128*128 fp32 transposed Wa
  int* deg    = (int*)(WaT + 3 * D * D);  // N  (zeroed: deg,cursor,tcnt,tcur)
  int* cursor = deg + N;                  // N
  int* tcnt   = cursor + N;               // T
  int* tcur   = tcnt + T;                 // T
  int* off    = tcur + T;                 // N+1
  int* toff   = off + N + 1;              // T+1
  int* esrc   = toff + T + 1;             // E  (CSR-ordered src values)
  int* pnid   = esrc + E;                 // P  (memset 0xFF -> -1)

  (void)hipMemsetAsync(deg, 0, (size_t)(2 * N + 2 * T) * sizeof(int), stream);
  (void)hipMemsetAsync(pnid, 0xFF, (size_t)P * sizeof(int), stream);

  int mNE = (E > N) ? E : N;
  int n8 = (int)(nD / 8);
  k_film<<<1, 2 * D, 0, stream>>>(gc, fw, fb, wgb, C);
  k_cast_x<<<(n8 + 255) / 256, 256, 0, stream>>>(x, xb, n8);
  k_cast_w<<<12, 256, 0, stream>>>(Wk, Wq, Wv, Wa, Wt, WaT);
  k_count<<<(mNE + 255) / 256, 256, 0, stream>>>(dst, ntype, deg, tcnt, N, E);
  k_scan<<<1, 1024, 0, stream>>>(deg, off, tcnt, toff, N, E);
  k_scatter<<<(mNE + 255) / 256, 256, 0, stream>>>(dst, src, ntype, off, toff,
                                                   cursor, tcur, esrc, pnid, N, E);
  k_proj_m<<<dim3(gridP, 3, 1), 256, 0, stream>>>(xb, pnid, ntype, Wt, rel_att,
                                                  rel_msg, rel_pri, kmpk, wqt);
  k_agg<<<N, D, 0, stream>>>(esrc, off, kmpk, wqt, whagg, N);
  k_out<<<gridO, 128, 0, stream>>>(whagg, pnid, ntype, WaT, x, skip, ln_g, ln_b,
                                   wgb, out);
}

// Round 16
// 241.179 us; speedup vs baseline: 1.0429x; 1.0429x over previous
//
#include <hip/hip_runtime.h>
#include <hip/hip_bf16.h>

constexpr int D  = 128;
constexpr int H  = 8;
constexpr int DH = 16;
constexpr int NB  = 16;  // nodes per MFMA tile / type-bucket alignment
constexpr int NBO = 8;   // nodes per k_out tile
constexpr int T  = 3;

typedef __attribute__((ext_vector_type(8))) short bf16x8;
typedef __attribute__((ext_vector_type(4))) float f32x4;

__device__ inline unsigned short f2bf(float f) {  // fp32 -> bf16 bits (RNE)
  unsigned u = __float_as_uint(f);
  unsigned r = u + 0x7fffu + ((u >> 16) & 1u);
  return (unsigned short)(r >> 16);
}

// ---------- FiLM: gb[0:128]=gamma, gb[128:256]=beta ----------
__global__ void k_film(const float* __restrict__ gc, const float* __restrict__ fw,
                       const float* __restrict__ fb, float* __restrict__ gb, int C) {
  int j = threadIdx.x;  // 256 threads
  float acc = fb[j];
  for (int c = 0; c < C; ++c) acc += gc[c] * fw[c * 256 + j];
  gb[j] = acc;
}

// ---------- cast x -> bf16 (8 elems/thread) ----------
__global__ void k_cast_x(const float* __restrict__ x, unsigned short* __restrict__ xb,
                         int n8) {
  int i = blockIdx.x * blockDim.x + threadIdx.x;
  if (i >= n8) return;
  const float4* p = (const float4*)(x + (size_t)i * 8);
  float4 a = p[0], b = p[1];
  ushort4 o0 = {f2bf(a.x), f2bf(a.y), f2bf(a.z), f2bf(a.w)};
  ushort4 o1 = {f2bf(b.x), f2bf(b.y), f2bf(b.z), f2bf(b.w)};
  ushort4* q = (ushort4*)(xb + (size_t)i * 8);
  q[0] = o0;
  q[1] = o1;
}

// ---------- cast+transpose Wk/Wq/Wv -> Wt[m][t][col][k] bf16 ----------
__global__ void k_cast_w(const float* __restrict__ Wk, const float* __restrict__ Wq,
                         const float* __restrict__ Wv, unsigned short* __restrict__ Wt) {
  int m = blockIdx.x / T, t = blockIdx.x % T;  // 9 blocks
  const float* W = (m == 0 ? Wk : m == 1 ? Wq : Wv) + (size_t)t * (D * D);
  unsigned short* o = Wt + ((size_t)m * T + t) * (D * D);
  for (int idx = threadIdx.x; idx < D * D; idx += blockDim.x) {
    int d = idx >> 7, c = idx & 127;          // read coalesced in c
    o[(size_t)c * D + d] = f2bf(W[idx]);      // transposed write
  }
}

// ---------- count in-degree + type histogram (wave-aggregated) ----------
__global__ void k_count(const int* __restrict__ dst, const int* __restrict__ ntype,
                        int* __restrict__ deg, int* __restrict__ tcnt, int N, int E) {
  int i = blockIdx.x * blockDim.x + threadIdx.x;
  if (i < E) atomicAdd(deg + dst[i], 1);
  int t = (i < N) ? ntype[i] : -1;
  int lane = threadIdx.x & 63;
#pragma unroll
  for (int tt = 0; tt < T; ++tt) {
    unsigned long long mask = __ballot(t == tt);
    int cnt = __popcll(mask);
    if (cnt > 0 && lane == (__ffsll((long long)mask) - 1))
      atomicAdd(tcnt + tt, cnt);
  }
}

// ---------- exclusive prefix sum over deg -> off[0..N]; also toff from tcnt ----------
__global__ void k_scan(const int* __restrict__ deg, int* __restrict__ off,
                       const int* __restrict__ tcnt, int* __restrict__ toff,
                       int N, int E) {
  __shared__ int wsum[16];
  __shared__ int base_s;
  int tid = threadIdx.x;          // 0..1023
  int lane = tid & 63, w = tid >> 6;
  if (tid == 0) {
    base_s = 0;
    toff[0] = 0;
    for (int t = 0; t < T; ++t) toff[t + 1] = toff[t] + ((tcnt[t] + NB - 1) / NB) * NB;
  }
  __syncthreads();
  for (int start = 0; start < N; start += 1024) {
    int i = start + tid;
    int v = (i < N) ? deg[i] : 0;
    int x = v;
#pragma unroll
    for (int o = 1; o < 64; o <<= 1) {
      int y = __shfl_up(x, o);
      if (lane >= o) x += y;
    }
    if (lane == 63) wsum[w] = x;
    __syncthreads();
    if (w == 0 && lane < 16) {
      int s = wsum[lane];
#pragma unroll
      for (int o = 1; o < 16; o <<= 1) {
        int y = __shfl_up(s, o);
        if (lane >= o) s += y;
      }
      wsum[lane] = s;
    }
    __syncthreads();
    int waveoff = (w > 0) ? wsum[w - 1] : 0;
    if (i < N) off[i] = base_s + waveoff + x - v;
    __syncthreads();
    if (tid == 0) base_s += wsum[15];
    __syncthreads();
  }
  if (tid == 0) off[N] = E;
}

// ---------- scatter: edges -> CSR src values; nodes -> type buckets ----------
__global__ void k_scatter(const int* __restrict__ dst, const int* __restrict__ src,
                          const int* __restrict__ ntype,
                          const int* __restrict__ off, const int* __restrict__ toff,
                          int* __restrict__ cursor, int* __restrict__ tcur,
                          int* __restrict__ esrc, int* __restrict__ pnid, int N, int E) {
  int i = blockIdx.x * blockDim.x + threadIdx.x;
  if (i < E) {
    int d = dst[i];
    int pos = atomicAdd(cursor + d, 1);
    esrc[off[d] + pos] = src[i];
  }
  int t = (i < N) ? ntype[i] : -1;
  int lane = threadIdx.x & 63;
#pragma unroll
  for (int tt = 0; tt < T; ++tt) {
    unsigned long long mask = __ballot(t == tt);
    int cnt = __popcll(mask);
    if (cnt == 0) continue;
    int leader = __ffsll((long long)mask) - 1;
    int base = 0;
    if (lane == leader) base = atomicAdd(tcur + tt, cnt);
    base = __shfl(base, leader);
    if (t == tt) {
      int rank = __popcll(mask & ((1ull << lane) - 1ull));
      pnid[toff[tt] + base + rank] = i;
    }
  }
}

// ---------- MFMA typed projection: 16 nodes x 128 out, bf16 in, fp32 acc.
//            blockIdx.y: 0=k, 1=q(->qt), 2=v(->mt). 256 thr = 4 waves, each
//            wave owns 32 output cols (2 col-tiles of 16).
//            A-frag: lane l elem i = A[l&15][(l>>4)*8+i]  (row-major)
//            B-frag: lane l elem i = B[(l>>4)*8+i][l&15]  (Wt col-major [c][k])
//            D: col = lane&15, row = (lane>>4)*4+reg  [verified r10/r14] ----------
__global__ void __launch_bounds__(256)
k_proj_m(const unsigned short* __restrict__ xb, const int* __restrict__ pnid,
         const int* __restrict__ ntype, const unsigned short* __restrict__ Wt,
         const float* __restrict__ ra_, const float* __restrict__ rm_,
         const float* __restrict__ rp,
         unsigned int* __restrict__ kmpk, float* __restrict__ oqt) {
  int b = blockIdx.x, which = blockIdx.y;
  int tid = threadIdx.x;
  int w = tid >> 6, l = tid & 63;
  __shared__ int nid_s[NB];
  if (tid < NB) nid_s[tid] = pnid[b * NB + tid];
  __syncthreads();
  int tfirst = -1;
#pragma unroll
  for (int nn = 0; nn < NB; ++nn) if (tfirst < 0 && nid_s[nn] >= 0) tfirst = ntype[nid_s[nn]];
  if (tfirst < 0) return;  // fully-padded block

  int arow = l & 15, kg = l >> 4;
  int anid = nid_s[arow];
  if (anid < 0) anid = 0;  // clamp: garbage rows never written back
  const unsigned short* abase = xb + (size_t)anid * D + kg * 8;
  const unsigned short* wbase = Wt + ((size_t)which * T + tfirst) * (D * D);
  int col0 = w * 32 + (l & 15);
  const unsigned short* b0 = wbase + (size_t)col0 * D + kg * 8;
  const unsigned short* b1 = b0 + (size_t)16 * D;
  f32x4 acc0 = {0.f, 0.f, 0.f, 0.f}, acc1 = {0.f, 0.f, 0.f, 0.f};
#pragma unroll
  for (int ks = 0; ks < 4; ++ks) {
    bf16x8 af = *(const bf16x8*)(abase + ks * 32);
    bf16x8 bf0 = *(const bf16x8*)(b0 + ks * 32);
    bf16x8 bf1 = *(const bf16x8*)(b1 + ks * 32);
    acc0 = __builtin_amdgcn_mfma_f32_16x16x32_bf16(af, bf0, acc0, 0, 0, 0);
    acc1 = __builtin_amdgcn_mfma_f32_16x16x32_bf16(af, bf1, acc1, 0, 0, 0);
  }

  int o = l & 15, kg4 = (l >> 4) * 4, gbase = l & 48;
  unsigned short* kb = (unsigned short*)kmpk;
  if (which == 0) {  // k -> low bf16 half
#pragma unroll
    for (int ct = 0; ct < 2; ++ct) {
      f32x4 acc = ct ? acc1 : acc0;
      int col = w * 32 + ct * 16 + o;
#pragma unroll
      for (int r = 0; r < 4; ++r) {
        int nid = nid_s[kg4 + r];
        if (nid >= 0) kb[((size_t)nid * D + col) * 2] = f2bf(acc[r]);
      }
    }
  } else if (which == 1) {  // q -> qt (rel_att transform + rel_pri/4 scale)
#pragma unroll
    for (int ct = 0; ct < 2; ++ct) {
      f32x4 acc = ct ? acc1 : acc0;
      int h = 2 * w + ct;
      int col = h * 16 + o;
      float raz[16];
#pragma unroll
      for (int z = 0; z < 16; ++z) raz[z] = ra_[h * 256 + o * 16 + z];
      float rph = rp[h] * 0.25f;
#pragma unroll
      for (int r = 0; r < 4; ++r) {
        float s = 0.f;
#pragma unroll
        for (int z = 0; z < 16; ++z) s += raz[z] * __shfl(acc[r], gbase | z);
        int nid = nid_s[kg4 + r];
        if (nid >= 0) oqt[(size_t)nid * D + col] = s * rph;
      }
    }
  } else {  // v -> mt (rel_msg transform) -> high bf16 half
#pragma unroll
    for (int ct = 0; ct < 2; ++ct) {
      f32x4 acc = ct ? acc1 : acc0;
      int h = 2 * w + ct;
      int col = h * 16 + o;
      float rmz[16];
#pragma unroll
      for (int z = 0; z < 16; ++z) rmz[z] = rm_[h * 256 + z * 16 + o];
#pragma unroll
      for (int r = 0; r < 4; ++r) {
        float s = 0.f;
#pragma unroll
        for (int z = 0; z < 16; ++z) s += rmz[z] * __shfl(acc[r], gbase | z);
        int nid = nid_s[kg4 + r];
        if (nid >= 0) kb[((size_t)nid * D + col) * 2 + 1] = f2bf(s);
      }
    }
  }
}

// ---------- per-node online-softmax aggregation (4-way unrolled) -> fp32 hagg ----------
__global__ void k_agg(const int* __restrict__ esrc, const int* __restrict__ off,
                      const unsigned int* __restrict__ kmpk,
                      const float* __restrict__ qt,
                      float* __restrict__ hagg, int N) {
  int n = blockIdx.x;
  int j = threadIdx.x;  // 0..127
  float qv = qt[(size_t)n * D + j];
  int i0 = off[n], i1 = off[n + 1];
  float m = -INFINITY, ssum = 0.f, acc = 0.f;
  int i = i0;
  for (; i + 4 <= i1; i += 4) {
    int s0 = esrc[i], s1 = esrc[i + 1], s2 = esrc[i + 2], s3 = esrc[i + 3];
    unsigned p0 = kmpk[(size_t)s0 * D + j];
    unsigned p1 = kmpk[(size_t)s1 * D + j];
    unsigned p2 = kmpk[(size_t)s2 * D + j];
    unsigned p3 = kmpk[(size_t)s3 * D + j];
    float kv0 = __uint_as_float(p0 << 16), mv0 = __uint_as_float(p0 & 0xffff0000u);
    float kv1 = __uint_as_float(p1 << 16), mv1 = __uint_as_float(p1 & 0xffff0000u);
    float kv2 = __uint_as_float(p2 << 16), mv2 = __uint_as_float(p2 & 0xffff0000u);
    float kv3 = __uint_as_float(p3 << 16), mv3 = __uint_as_float(p3 & 0xffff0000u);
    float a0 = kv0 * qv, a1 = kv1 * qv, a2 = kv2 * qv, a3 = kv3 * qv;
#pragma unroll
    for (int o = 8; o >= 1; o >>= 1) {
      a0 += __shfl_xor(a0, o);
      a1 += __shfl_xor(a1, o);
      a2 += __shfl_xor(a2, o);
      a3 += __shfl_xor(a3, o);
    }
    float mn = fmaxf(fmaxf(m, fmaxf(a0, a1)), fmaxf(a2, a3));
    float sc = __expf(m - mn);
    float w0 = __expf(a0 - mn), w1 = __expf(a1 - mn);
    float w2 = __expf(a2 - mn), w3 = __expf(a3 - mn);
    ssum = ssum * sc + (w0 + w1) + (w2 + w3);
    acc = acc * sc + (w0 * mv0 + w1 * mv1) + (w2 * mv2 + w3 * mv3);
    m = mn;
  }
  for (; i < i1; ++i) {
    int sn = esrc[i];
    unsigned p = kmpk[(size_t)sn * D + j];
    float kv = __uint_as_float(p << 16), mv = __uint_as_float(p & 0xffff0000u);
    float a = kv * qv;
#pragma unroll
    for (int o = 8; o >= 1; o >>= 1) a += __shfl_xor(a, o);
    float mn = fmaxf(m, a);
    float sc = __expf(m - mn);
    float wgt = __expf(a - mn);
    ssum = ssum * sc + wgt;
    acc = acc * sc + wgt * mv;
    m = mn;
  }
  hagg[(size_t)n * D + j] = (ssum > 0.f) ? acc / ssum : 0.f;
}

// ---------- fp32 Wa GEMM (coalesced weights + float4 LDS reads) + epilogue ----------
__global__ void __launch_bounds__(128)
k_out(const float* __restrict__ hagg, const int* __restrict__ pnid,
      const int* __restrict__ ntype, const float* __restrict__ Wa,
      const float* __restrict__ x, const float* __restrict__ skip,
      const float* __restrict__ ln_g, const float* __restrict__ ln_b,
      const float* __restrict__ gb, float* __restrict__ out) {
  int b = blockIdx.x, j = threadIdx.x;  // 128 threads
  __shared__ __align__(16) float hs[NBO][D];
  __shared__ int nid_s[NBO];
  __shared__ float red[2][NBO][2];
  if (j < NBO) nid_s[j] = pnid[b * NBO + j];
  __syncthreads();
  for (int idx = j; idx < NBO * D; idx += 128) {
    int nn = idx >> 7, col = idx & 127;
    int nid = nid_s[nn];
    hs[nn][col] = (nid >= 0) ? hagg[(size_t)nid * D + col] : 0.f;
  }
  __syncthreads();
  int tfirst = -1;
#pragma unroll
  for (int nn = 0; nn < NBO; ++nn) if (tfirst < 0 && nid_s[nn] >= 0) tfirst = ntype[nid_s[nn]];
  if (tfirst < 0) return;
  const float* wp = Wa + (size_t)tfirst * (D * D) + j;  // coalesced across j
  float acc[NBO];
#pragma unroll
  for (int nn = 0; nn < NBO; ++nn) acc[nn] = 0.f;
#pragma unroll 2
  for (int d = 0; d < D; d += 4) {
    float w0 = wp[(size_t)d * D];
    float w1 = wp[(size_t)(d + 1) * D];
    float w2 = wp[(size_t)(d + 2) * D];
    float w3 = wp[(size_t)(d + 3) * D];
#pragma unroll
    for (int nn = 0; nn < NBO; ++nn) {
      float4 h4 = *(const float4*)(&hs[nn][d]);  // ds_read_b128 broadcast
      acc[nn] = fmaf(h4.x, w0, acc[nn]);
      acc[nn] = fmaf(h4.y, w1, acc[nn]);
      acc[nn] = fmaf(h4.z, w2, acc[nn]);
      acc[nn] = fmaf(h4.w, w3, acc[nn]);
    }
  }
  float alpha = 1.f / (1.f + __expf(-skip[tfirst]));
  int w = j >> 6;
  float hv[NBO];
#pragma unroll
  for (int nn = 0; nn < NBO; ++nn) {
    int nid = nid_s[nn];
    float xv = (nid >= 0) ? x[(size_t)nid * D + j] : 0.f;
    hv[nn] = (nid >= 0) ? (acc[nn] * alpha + xv * (1.f - alpha)) : 0.f;
    float s1 = hv[nn], s2 = hv[nn] * hv[nn];
#pragma unroll
    for (int o = 1; o < 64; o <<= 1) {
      s1 += __shfl_xor(s1, o);
      s2 += __shfl_xor(s2, o);
    }
    if ((j & 63) == 0) { red[w][nn][0] = s1; red[w][nn][1] = s2; }
  }
  __syncthreads();
  float gj = ln_g[j], bj = ln_b[j], gmj = gb[j], gbj = gb[D + j];
#pragma unroll
  for (int nn = 0; nn < NBO; ++nn) {
    int nid = nid_s[nn];
    if (nid < 0) continue;
    float mu = (red[0][nn][0] + red[1][nn][0]) * (1.f / D);
    float m2 = (red[0][nn][1] + red[1][nn][1]) * (1.f / D);
    float var = m2 - mu * mu;
    float xv = x[(size_t)nid * D + j];
    float y = (hv[nn] - mu) * rsqrtf(var + 1e-5f) * gj + bj + xv;
    out[(size_t)nid * D + j] = gmj * y + gbj;
  }
}

extern "C" void kernel_launch(void* const* d_in, const int* in_sizes, int n_in,
                              void* d_out, int out_size, void* d_ws, size_t ws_size,
                              hipStream_t stream) {
  const float* x       = (const float*)d_in[0];
  const float* gc      = (const float*)d_in[1];
  const float* Wk      = (const float*)d_in[2];
  const float* Wq      = (const float*)d_in[3];
  const float* Wv      = (const float*)d_in[4];
  const float* rel_att = (const float*)d_in[5];
  const float* rel_msg = (const float*)d_in[6];
  const float* rel_pri = (const float*)d_in[7];
  const float* Wa      = (const float*)d_in[8];
  const float* skip    = (const float*)d_in[9];
  const float* ln_g    = (const float*)d_in[10];
  const float* ln_b    = (const float*)d_in[11];
  const float* fw      = (const float*)d_in[12];
  const float* fb      = (const float*)d_in[13];
  const int* ntype     = (const int*)d_in[14];
  const int* src       = (const int*)d_in[15];
  const int* dst       = (const int*)d_in[16];
  float* out = (float*)d_out;

  int N = in_sizes[0] / D;
  int C = in_sizes[1];
  int E = in_sizes[15];

  int gridP = (N + NB - 1) / NB + T;  // upper bound on padded 16-node tiles
  int P = gridP * NB;                 // padded node-list size
  int gridO = P / NBO;                // 8-node tiles

  float* ws = (float*)d_ws;
  size_t nD = (size_t)N * D;
  float* wqt   = ws;                                 // N*128 fp32 qt (scaled)
  float* whagg = wqt + nD;                           // N*128 fp32 h_agg
  float* wgb   = whagg + nD;                         // 256 gamma|beta
  unsigned int*   kmpk = (unsigned int*)(wgb + 256); // N*128 packed {k,mt} bf16
  unsigned short* xb   = (unsigned short*)(kmpk + nD);  // N*128 bf16 x
  unsigned short* Wt   = xb + nD;                    // 3*3*128*128 bf16 col-major
  int* deg    = (int*)(Wt + 9 * D * D);  // N  (zeroed: deg,cursor,tcnt,tcur)
  int* cursor = deg + N;                 // N
  int* tcnt   = cursor + N;              // T
  int* tcur   = tcnt + T;                // T
  int* off    = tcur + T;                // N+1
  int* toff   = off + N + 1;             // T+1
  int* esrc   = toff + T + 1;            // E  (CSR-ordered src values)
  int* pnid   = esrc + E;                // P  (memset 0xFF -> -1)

  (void)hipMemsetAsync(deg, 0, (size_t)(2 * N + 2 * T) * sizeof(int), stream);
  (void)hipMemsetAsync(pnid, 0xFF, (size_t)P * sizeof(int), stream);

  int mNE = (E > N) ? E : N;
  int n8 = (int)(nD / 8);
  k_film<<<1, 2 * D, 0, stream>>>(gc, fw, fb, wgb, C);
  k_cast_x<<<(n8 + 255) / 256, 256, 0, stream>>>(x, xb, n8);
  k_cast_w<<<9, 256, 0, stream>>>(Wk, Wq, Wv, Wt);
  k_count<<<(mNE + 255) / 256, 256, 0, stream>>>(dst, ntype, deg, tcnt, N, E);
  k_scan<<<1, 1024, 0, stream>>>(deg, off, tcnt, toff, N, E);
  k_scatter<<<(mNE + 255) / 256, 256, 0, stream>>>(dst, src, ntype, off, toff,
                                                   cursor, tcur, esrc, pnid, N, E);
  k_proj_m<<<dim3(gridP, 3, 1), 256, 0, stream>>>(xb, pnid, ntype, Wt, rel_att,
                                                  rel_msg, rel_pri, kmpk, wqt);
  k_agg<<<N, D, 0, stream>>>(esrc, off, kmpk, wqt, whagg, N);
  k_out<<<gridO, 128, 0, stream>>>(whagg, pnid, ntype, Wa, x, skip, ln_g, ln_b,
                                   wgb, out);
}

// Round 17
// 211.180 us; speedup vs baseline: 1.1910x; 1.1421x over previous
//
#include <hip/hip_runtime.h>
#include <hip/hip_bf16.h>

constexpr int D  = 128;
constexpr int H  = 8;
constexpr int DH = 16;
constexpr int NB  = 16;  // nodes per MFMA tile / type-bucket alignment
constexpr int NBO = 16;  // nodes per k_out tile
constexpr int T  = 3;

typedef __attribute__((ext_vector_type(8))) short bf16x8;
typedef __attribute__((ext_vector_type(4))) float f32x4;

__device__ inline unsigned short f2bf(float f) {  // fp32 -> bf16 bits (RNE)
  unsigned u = __float_as_uint(f);
  unsigned r = u + 0x7fffu + ((u >> 16) & 1u);
  return (unsigned short)(r >> 16);
}

// ---------- fused prep: [0,BE): edge-count+type-hist; [BE,BE+BX): cast x;
//            [BE+BX, BE+BX+9): cast W; last block: FiLM ----------
__global__ void k_prep(const int* __restrict__ dst, const int* __restrict__ ntype,
                       int* __restrict__ deg, int* __restrict__ tcnt, int N, int E,
                       const float* __restrict__ x, unsigned short* __restrict__ xb,
                       int n8,
                       const float* __restrict__ Wk, const float* __restrict__ Wq,
                       const float* __restrict__ Wv, unsigned short* __restrict__ Wt,
                       const float* __restrict__ gc, const float* __restrict__ fw,
                       const float* __restrict__ fb, float* __restrict__ gb, int C,
                       int BE, int BX) {
  int blk = blockIdx.x, tid = threadIdx.x;
  if (blk < BE) {  // edge in-degree count + node type histogram
    int i = blk * 256 + tid;
    if (i < E) atomicAdd(deg + dst[i], 1);
    int t = (i < N) ? ntype[i] : -1;
    int lane = tid & 63;
#pragma unroll
    for (int tt = 0; tt < T; ++tt) {
      unsigned long long mask = __ballot(t == tt);
      int cnt = __popcll(mask);
      if (cnt > 0 && lane == (__ffsll((long long)mask) - 1))
        atomicAdd(tcnt + tt, cnt);
    }
    return;
  }
  if (blk < BE + BX) {  // cast x -> bf16, 8 elems/thread
    int i = (blk - BE) * 256 + tid;
    if (i >= n8) return;
    const float4* p = (const float4*)(x + (size_t)i * 8);
    float4 a = p[0], b = p[1];
    ushort4 o0 = {f2bf(a.x), f2bf(a.y), f2bf(a.z), f2bf(a.w)};
    ushort4 o1 = {f2bf(b.x), f2bf(b.y), f2bf(b.z), f2bf(b.w)};
    ushort4* q = (ushort4*)(xb + (size_t)i * 8);
    q[0] = o0;
    q[1] = o1;
    return;
  }
  if (blk < BE + BX + 9) {  // cast+transpose Wk/Wq/Wv -> bf16 [col][k]
    int b2 = blk - BE - BX;
    int m = b2 / T, t = b2 % T;
    const float* W = (m == 0 ? Wk : m == 1 ? Wq : Wv) + (size_t)t * (D * D);
    unsigned short* o = Wt + ((size_t)m * T + t) * (D * D);
    for (int idx = tid; idx < D * D; idx += 256) {
      int d = idx >> 7, c = idx & 127;
      o[(size_t)c * D + d] = f2bf(W[idx]);
    }
    return;
  }
  // FiLM: gb[0:128]=gamma, gb[128:256]=beta (256 threads)
  float acc = fb[tid];
  for (int c = 0; c < C; ++c) acc += gc[c] * fw[c * 256 + tid];
  gb[tid] = acc;
}

// ---------- exclusive prefix sum over deg -> off[0..N]; also toff from tcnt ----------
__global__ void k_scan(const int* __restrict__ deg, int* __restrict__ off,
                       const int* __restrict__ tcnt, int* __restrict__ toff,
                       int N, int E) {
  __shared__ int wsum[16];
  __shared__ int base_s;
  int tid = threadIdx.x;          // 0..1023
  int lane = tid & 63, w = tid >> 6;
  if (tid == 0) {
    base_s = 0;
    toff[0] = 0;
    for (int t = 0; t < T; ++t) toff[t + 1] = toff[t] + ((tcnt[t] + NB - 1) / NB) * NB;
  }
  __syncthreads();
  for (int start = 0; start < N; start += 1024) {
    int i = start + tid;
    int v = (i < N) ? deg[i] : 0;
    int x = v;
#pragma unroll
    for (int o = 1; o < 64; o <<= 1) {
      int y = __shfl_up(x, o);
      if (lane >= o) x += y;
    }
    if (lane == 63) wsum[w] = x;
    __syncthreads();
    if (w == 0 && lane < 16) {
      int s = wsum[lane];
#pragma unroll
      for (int o = 1; o < 16; o <<= 1) {
        int y = __shfl_up(s, o);
        if (lane >= o) s += y;
      }
      wsum[lane] = s;
    }
    __syncthreads();
    int waveoff = (w > 0) ? wsum[w - 1] : 0;
    if (i < N) off[i] = base_s + waveoff + x - v;
    __syncthreads();
    if (tid == 0) base_s += wsum[15];
    __syncthreads();
  }
  if (tid == 0) off[N] = E;
}

// ---------- scatter: edges -> CSR src values; nodes -> type buckets ----------
__global__ void k_scatter(const int* __restrict__ dst, const int* __restrict__ src,
                          const int* __restrict__ ntype,
                          const int* __restrict__ off, const int* __restrict__ toff,
                          int* __restrict__ cursor, int* __restrict__ tcur,
                          int* __restrict__ esrc, int* __restrict__ pnid, int N, int E) {
  int i = blockIdx.x * blockDim.x + threadIdx.x;
  if (i < E) {
    int d = dst[i];
    int pos = atomicAdd(cursor + d, 1);
    esrc[off[d] + pos] = src[i];
  }
  int t = (i < N) ? ntype[i] : -1;
  int lane = threadIdx.x & 63;
#pragma unroll
  for (int tt = 0; tt < T; ++tt) {
    unsigned long long mask = __ballot(t == tt);
    int cnt = __popcll(mask);
    if (cnt == 0) continue;
    int leader = __ffsll((long long)mask) - 1;
    int base = 0;
    if (lane == leader) base = atomicAdd(tcur + tt, cnt);
    base = __shfl(base, leader);
    if (t == tt) {
      int rank = __popcll(mask & ((1ull << lane) - 1ull));
      pnid[toff[tt] + base + rank] = i;
    }
  }
}

// ---------- MFMA typed projection: 16 nodes x 128 out, bf16 in, fp32 acc.
//            blockIdx.y: 0=k, 1=q(->qt), 2=v(->mt). 256 thr = 4 waves, each
//            wave owns 32 output cols (2 col-tiles of 16).
//            A-frag: lane l elem i = A[l&15][(l>>4)*8+i]  (row-major)
//            B-frag: lane l elem i = B[(l>>4)*8+i][l&15]  (Wt col-major [c][k])
//            D: col = lane&15, row = (lane>>4)*4+reg  [verified r10/r14] ----------
__global__ void __launch_bounds__(256)
k_proj_m(const unsigned short* __restrict__ xb, const int* __restrict__ pnid,
         const int* __restrict__ ntype, const unsigned short* __restrict__ Wt,
         const float* __restrict__ ra_, const float* __restrict__ rm_,
         const float* __restrict__ rp,
         unsigned int* __restrict__ kmpk, float* __restrict__ oqt) {
  int b = blockIdx.x, which = blockIdx.y;
  int tid = threadIdx.x;
  int w = tid >> 6, l = tid & 63;
  __shared__ int nid_s[NB];
  if (tid < NB) nid_s[tid] = pnid[b * NB + tid];
  __syncthreads();
  int tfirst = -1;
#pragma unroll
  for (int nn = 0; nn < NB; ++nn) if (tfirst < 0 && nid_s[nn] >= 0) tfirst = ntype[nid_s[nn]];
  if (tfirst < 0) return;  // fully-padded block

  int arow = l & 15, kg = l >> 4;
  int anid = nid_s[arow];
  if (anid < 0) anid = 0;  // clamp: garbage rows never written back
  const unsigned short* abase = xb + (size_t)anid * D + kg * 8;
  const unsigned short* wbase = Wt + ((size_t)which * T + tfirst) * (D * D);
  int col0 = w * 32 + (l & 15);
  const unsigned short* b0 = wbase + (size_t)col0 * D + kg * 8;
  const unsigned short* b1 = b0 + (size_t)16 * D;
  f32x4 acc0 = {0.f, 0.f, 0.f, 0.f}, acc1 = {0.f, 0.f, 0.f, 0.f};
#pragma unroll
  for (int ks = 0; ks < 4; ++ks) {
    bf16x8 af = *(const bf16x8*)(abase + ks * 32);
    bf16x8 bf0 = *(const bf16x8*)(b0 + ks * 32);
    bf16x8 bf1 = *(const bf16x8*)(b1 + ks * 32);
    acc0 = __builtin_amdgcn_mfma_f32_16x16x32_bf16(af, bf0, acc0, 0, 0, 0);
    acc1 = __builtin_amdgcn_mfma_f32_16x16x32_bf16(af, bf1, acc1, 0, 0, 0);
  }

  int o = l & 15, kg4 = (l >> 4) * 4, gbase = l & 48;
  unsigned short* kb = (unsigned short*)kmpk;
  if (which == 0) {  // k -> low bf16 half
#pragma unroll
    for (int ct = 0; ct < 2; ++ct) {
      f32x4 acc = ct ? acc1 : acc0;
      int col = w * 32 + ct * 16 + o;
#pragma unroll
      for (int r = 0; r < 4; ++r) {
        int nid = nid_s[kg4 + r];
        if (nid >= 0) kb[((size_t)nid * D + col) * 2] = f2bf(acc[r]);
      }
    }
  } else if (which == 1) {  // q -> qt (rel_att transform + rel_pri/4 scale)
#pragma unroll
    for (int ct = 0; ct < 2; ++ct) {
      f32x4 acc = ct ? acc1 : acc0;
      int h = 2 * w + ct;
      int col = h * 16 + o;
      float raz[16];
#pragma unroll
      for (int z = 0; z < 16; ++z) raz[z] = ra_[h * 256 + o * 16 + z];
      float rph = rp[h] * 0.25f;
#pragma unroll
      for (int r = 0; r < 4; ++r) {
        float s = 0.f;
#pragma unroll
        for (int z = 0; z < 16; ++z) s += raz[z] * __shfl(acc[r], gbase | z);
        int nid = nid_s[kg4 + r];
        if (nid >= 0) oqt[(size_t)nid * D + col] = s * rph;
      }
    }
  } else {  // v -> mt (rel_msg transform) -> high bf16 half
#pragma unroll
    for (int ct = 0; ct < 2; ++ct) {
      f32x4 acc = ct ? acc1 : acc0;
      int h = 2 * w + ct;
      int col = h * 16 + o;
      float rmz[16];
#pragma unroll
      for (int z = 0; z < 16; ++z) rmz[z] = rm_[h * 256 + z * 16 + o];
#pragma unroll
      for (int r = 0; r < 4; ++r) {
        float s = 0.f;
#pragma unroll
        for (int z = 0; z < 16; ++z) s += rmz[z] * __shfl(acc[r], gbase | z);
        int nid = nid_s[kg4 + r];
        if (nid >= 0) kb[((size_t)nid * D + col) * 2 + 1] = f2bf(s);
      }
    }
  }
}

// ---------- per-node softmax aggregation, no max-shift (|a| << 1, exp safe),
//            4-way unrolled, fully pipelined accumulation ----------
__global__ void k_agg(const int* __restrict__ esrc, const int* __restrict__ off,
                      const unsigned int* __restrict__ kmpk,
                      const float* __restrict__ qt,
                      float* __restrict__ hagg, int N) {
  int n = blockIdx.x;
  int j = threadIdx.x;  // 0..127
  float qv = qt[(size_t)n * D + j];
  int i0 = off[n], i1 = off[n + 1];
  float ssum = 0.f, acc = 0.f;
  int i = i0;
  for (; i + 4 <= i1; i += 4) {
    int s0 = esrc[i], s1 = esrc[i + 1], s2 = esrc[i + 2], s3 = esrc[i + 3];
    unsigned p0 = kmpk[(size_t)s0 * D + j];
    unsigned p1 = kmpk[(size_t)s1 * D + j];
    unsigned p2 = kmpk[(size_t)s2 * D + j];
    unsigned p3 = kmpk[(size_t)s3 * D + j];
    float kv0 = __uint_as_float(p0 << 16), mv0 = __uint_as_float(p0 & 0xffff0000u);
    float kv1 = __uint_as_float(p1 << 16), mv1 = __uint_as_float(p1 & 0xffff0000u);
    float kv2 = __uint_as_float(p2 << 16), mv2 = __uint_as_float(p2 & 0xffff0000u);
    float kv3 = __uint_as_float(p3 << 16), mv3 = __uint_as_float(p3 & 0xffff0000u);
    float a0 = kv0 * qv, a1 = kv1 * qv, a2 = kv2 * qv, a3 = kv3 * qv;
#pragma unroll
    for (int o = 8; o >= 1; o >>= 1) {
      a0 += __shfl_xor(a0, o);
      a1 += __shfl_xor(a1, o);
      a2 += __shfl_xor(a2, o);
      a3 += __shfl_xor(a3, o);
    }
    float w0 = __expf(a0), w1 = __expf(a1), w2 = __expf(a2), w3 = __expf(a3);
    ssum += (w0 + w1) + (w2 + w3);
    acc += (w0 * mv0 + w1 * mv1) + (w2 * mv2 + w3 * mv3);
  }
  for (; i < i1; ++i) {
    int sn = esrc[i];
    unsigned p = kmpk[(size_t)sn * D + j];
    float kv = __uint_as_float(p << 16), mv = __uint_as_float(p & 0xffff0000u);
    float a = kv * qv;
#pragma unroll
    for (int o = 8; o >= 1; o >>= 1) a += __shfl_xor(a, o);
    float wgt = __expf(a);
    ssum += wgt;
    acc += wgt * mv;
  }
  hagg[(size_t)n * D + j] = (ssum > 0.f) ? acc / ssum : 0.f;
}

// ---------- fp32 Wa GEMM, 16 nodes/block, 256 thr (2 col-groups x 8 nodes)
//            + skip-mix + LayerNorm + residual + FiLM ----------
__global__ void __launch_bounds__(256)
k_out(const float* __restrict__ hagg, const int* __restrict__ pnid,
      const int* __restrict__ ntype, const float* __restrict__ Wa,
      const float* __restrict__ x, const float* __restrict__ skip,
      const float* __restrict__ ln_g, const float* __restrict__ ln_b,
      const float* __restrict__ gb, float* __restrict__ out) {
  int b = blockIdx.x, tid = threadIdx.x;
  int j = tid & 127, g = tid >> 7;  // g in {0,1}: nodes g*8 .. g*8+7
  __shared__ __align__(16) float hs[NBO][D];
  __shared__ int nid_s[NBO];
  __shared__ float red[4][8][2];  // [wave][local nn][s1,s2]
  if (tid < NBO) nid_s[tid] = pnid[b * NBO + tid];
  __syncthreads();
  for (int idx = tid; idx < NBO * D; idx += 256) {
    int nn = idx >> 7, col = idx & 127;
    int nid = nid_s[nn];
    hs[nn][col] = (nid >= 0) ? hagg[(size_t)nid * D + col] : 0.f;
  }
  __syncthreads();
  int tfirst = -1;
#pragma unroll
  for (int nn = 0; nn < NBO; ++nn) if (tfirst < 0 && nid_s[nn] >= 0) tfirst = ntype[nid_s[nn]];
  if (tfirst < 0) return;
  const float* wp = Wa + (size_t)tfirst * (D * D) + j;  // coalesced across j
  float acc[8];
#pragma unroll
  for (int nn = 0; nn < 8; ++nn) acc[nn] = 0.f;
#pragma unroll 2
  for (int d = 0; d < D; d += 4) {
    float w0 = wp[(size_t)d * D];
    float w1 = wp[(size_t)(d + 1) * D];
    float w2 = wp[(size_t)(d + 2) * D];
    float w3 = wp[(size_t)(d + 3) * D];
#pragma unroll
    for (int nn = 0; nn < 8; ++nn) {
      float4 h4 = *(const float4*)(&hs[g * 8 + nn][d]);  // ds_read_b128
      acc[nn] = fmaf(h4.x, w0, acc[nn]);
      acc[nn] = fmaf(h4.y, w1, acc[nn]);
      acc[nn] = fmaf(h4.z, w2, acc[nn]);
      acc[nn] = fmaf(h4.w, w3, acc[nn]);
    }
  }
  float alpha = 1.f / (1.f + __expf(-skip[tfirst]));
  int w = tid >> 6;  // 0..3
  float hv[8];
#pragma unroll
  for (int nn = 0; nn < 8; ++nn) {
    int nid = nid_s[g * 8 + nn];
    float xv = (nid >= 0) ? x[(size_t)nid * D + j] : 0.f;
    hv[nn] = (nid >= 0) ? (acc[nn] * alpha + xv * (1.f - alpha)) : 0.f;
    float s1 = hv[nn], s2 = hv[nn] * hv[nn];
#pragma unroll
    for (int o = 1; o < 64; o <<= 1) {
      s1 += __shfl_xor(s1, o);
      s2 += __shfl_xor(s2, o);
    }
    if ((tid & 63) == 0) { red[w][nn][0] = s1; red[w][nn][1] = s2; }
  }
  __syncthreads();
  float gj = ln_g[j], bj = ln_b[j], gmj = gb[j], gbj = gb[D + j];
#pragma unroll
  for (int nn = 0; nn < 8; ++nn) {
    int nid = nid_s[g * 8 + nn];
    if (nid < 0) continue;
    float mu = (red[2 * g][nn][0] + red[2 * g + 1][nn][0]) * (1.f / D);
    float m2 = (red[2 * g][nn][1] + red[2 * g + 1][nn][1]) * (1.f / D);
    float var = m2 - mu * mu;
    float xv = x[(size_t)nid * D + j];
    float y = (hv[nn] - mu) * rsqrtf(var + 1e-5f) * gj + bj + xv;
    out[(size_t)nid * D + j] = gmj * y + gbj;
  }
}

extern "C" void kernel_launch(void* const* d_in, const int* in_sizes, int n_in,
                              void* d_out, int out_size, void* d_ws, size_t ws_size,
                              hipStream_t stream) {
  const float* x       = (const float*)d_in[0];
  const float* gc      = (const float*)d_in[1];
  const float* Wk      = (const float*)d_in[2];
  const float* Wq      = (const float*)d_in[3];
  const float* Wv      = (const float*)d_in[4];
  const float* rel_att = (const float*)d_in[5];
  const float* rel_msg = (const float*)d_in[6];
  const float* rel_pri = (const float*)d_in[7];
  const float* Wa      = (const float*)d_in[8];
  const float* skip    = (const float*)d_in[9];
  const float* ln_g    = (const float*)d_in[10];
  const float* ln_b    = (const float*)d_in[11];
  const float* fw      = (const float*)d_in[12];
  const float* fb      = (const float*)d_in[13];
  const int* ntype     = (const int*)d_in[14];
  const int* src       = (const int*)d_in[15];
  const int* dst       = (const int*)d_in[16];
  float* out = (float*)d_out;

  int N = in_sizes[0] / D;
  int C = in_sizes[1];
  int E = in_sizes[15];

  int gridP = (N + NB - 1) / NB + T;  // upper bound on padded 16-node tiles
  int P = gridP * NB;                 // padded node-list size
  int gridO = P / NBO;                // 16-node tiles

  float* ws = (float*)d_ws;
  size_t nD = (size_t)N * D;
  float* wqt   = ws;                                 // N*128 fp32 qt (scaled)
  float* whagg = wqt + nD;                           // N*128 fp32 h_agg
  float* wgb   = whagg + nD;                         // 256 gamma|beta
  unsigned int*   kmpk = (unsigned int*)(wgb + 256); // N*128 packed {k,mt} bf16
  unsigned short* xb   = (unsigned short*)(kmpk + nD);  // N*128 bf16 x
  unsigned short* Wt   = xb + nD;                    // 3*3*128*128 bf16 col-major
  int* deg    = (int*)(Wt + 9 * D * D);  // N  (zeroed: deg,cursor,tcnt,tcur)
  int* cursor = deg + N;                 // N
  int* tcnt   = cursor + N;              // T
  int* tcur   = tcnt + T;                // T
  int* off    = tcur + T;                // N+1
  int* toff   = off + N + 1;             // T+1
  int* esrc   = toff + T + 1;            // E  (CSR-ordered src values)
  int* pnid   = esrc + E;                // P  (memset 0xFF -> -1)

  (void)hipMemsetAsync(deg, 0, (size_t)(2 * N + 2 * T) * sizeof(int), stream);
  (void)hipMemsetAsync(pnid, 0xFF, (size_t)P * sizeof(int), stream);

  int mNE = (E > N) ? E : N;
  int n8 = (int)(nD / 8);
  int BE = (mNE + 255) / 256;
  int BX = (n8 + 255) / 256;
  k_prep<<<BE + BX + 9 + 1, 256, 0, stream>>>(dst, ntype, deg, tcnt, N, E,
                                              x, xb, n8, Wk, Wq, Wv, Wt,
                                              gc, fw, fb, wgb, C, BE, BX);
  k_scan<<<1, 1024, 0, stream>>>(deg, off, tcnt, toff, N, E);
  k_scatter<<<(mNE + 255) / 256, 256, 0, stream>>>(dst, src, ntype, off, toff,
                                                   cursor, tcur, esrc, pnid, N, E);
  k_proj_m<<<dim3(gridP, 3, 1), 256, 0, stream>>>(xb, pnid, ntype, Wt, rel_att,
                                                  rel_msg, rel_pri, kmpk, wqt);
  k_agg<<<N, D, 0, stream>>>(esrc, off, kmpk, wqt, whagg, N);
  k_out<<<gridO, 256, 0, stream>>>(whagg, pnid, ntype, Wa, x, skip, ln_g, ln_b,
                                   wgb, out);
}

// Round 18
// 200.094 us; speedup vs baseline: 1.2570x; 1.0554x over previous
//
#include <hip/hip_runtime.h>
#include <hip/hip_bf16.h>

constexpr int D  = 128;
constexpr int H  = 8;
constexpr int DH = 16;
constexpr int NB  = 16;  // nodes per MFMA tile / type-bucket alignment
constexpr int NBO = 16;  // nodes per k_out tile
constexpr int T  = 3;

typedef __attribute__((ext_vector_type(8))) short bf16x8;
typedef __attribute__((ext_vector_type(4))) float f32x4;

__device__ inline unsigned short f2bf(float f) {  // fp32 -> bf16 bits (RNE)
  unsigned u = __float_as_uint(f);
  unsigned r = u + 0x7fffu + ((u >> 16) & 1u);
  return (unsigned short)(r >> 16);
}

// ---------- fused prep. Block roles (latency-bound tails FIRST):
//   blk 0: FiLM;  [1,10): cast_w;  [10,10+BE): edge count+hist;
//   [10+BE, 10+BE+BX): cast x ----------
__global__ void k_prep(const int* __restrict__ dst, const int* __restrict__ ntype,
                       int* __restrict__ deg, int* __restrict__ tcnt, int N, int E,
                       const float* __restrict__ x, unsigned short* __restrict__ xb,
                       int n8,
                       const float* __restrict__ Wk, const float* __restrict__ Wq,
                       const float* __restrict__ Wv, unsigned short* __restrict__ Wt,
                       const float* __restrict__ gc, const float* __restrict__ fw,
                       const float* __restrict__ fb, float* __restrict__ gb, int C,
                       int BE, int BX) {
  int blk = blockIdx.x, tid = threadIdx.x;
  if (blk == 0) {  // FiLM: gb[0:128]=gamma, gb[128:256]=beta (256 threads)
    float a0 = 0.f, a1 = 0.f, a2 = 0.f, a3 = 0.f;
    int c = 0;
    for (; c + 4 <= C; c += 4) {
      a0 += gc[c] * fw[c * 256 + tid];
      a1 += gc[c + 1] * fw[(c + 1) * 256 + tid];
      a2 += gc[c + 2] * fw[(c + 2) * 256 + tid];
      a3 += gc[c + 3] * fw[(c + 3) * 256 + tid];
    }
    float acc = fb[tid] + (a0 + a1) + (a2 + a3);
    for (; c < C; ++c) acc += gc[c] * fw[c * 256 + tid];
    gb[tid] = acc;
    return;
  }
  if (blk < 10) {  // cast+transpose Wk/Wq/Wv -> bf16 [col][k]; coalesced WRITES
    int b2 = blk - 1;
    int m = b2 / T, t = b2 % T;
    const float* W = (m == 0 ? Wk : m == 1 ? Wq : Wv) + (size_t)t * (D * D);
    unsigned short* o = Wt + ((size_t)m * T + t) * (D * D);
    for (int idx = tid; idx < D * D; idx += 256) {
      int c = idx >> 7, d = idx & 127;         // consecutive tid -> consecutive d
      o[(size_t)c * D + d] = f2bf(W[(size_t)d * D + c]);  // write coalesced; read L1-amortized
    }
    return;
  }
  if (blk < 10 + BE) {  // edge in-degree count + node type histogram
    int i = (blk - 10) * 256 + tid;
    if (i < E) atomicAdd(deg + dst[i], 1);
    int t = (i < N) ? ntype[i] : -1;
    int lane = tid & 63;
#pragma unroll
    for (int tt = 0; tt < T; ++tt) {
      unsigned long long mask = __ballot(t == tt);
      int cnt = __popcll(mask);
      if (cnt > 0 && lane == (__ffsll((long long)mask) - 1))
        atomicAdd(tcnt + tt, cnt);
    }
    return;
  }
  // cast x -> bf16, 8 elems/thread
  int i = (blk - 10 - BE) * 256 + tid;
  if (i >= n8) return;
  const float4* p = (const float4*)(x + (size_t)i * 8);
  float4 a = p[0], b = p[1];
  ushort4 o0 = {f2bf(a.x), f2bf(a.y), f2bf(a.z), f2bf(a.w)};
  ushort4 o1 = {f2bf(b.x), f2bf(b.y), f2bf(b.z), f2bf(b.w)};
  ushort4* q = (ushort4*)(xb + (size_t)i * 8);
  q[0] = o0;
  q[1] = o1;
}

// ---------- exclusive prefix sum over deg -> off[0..N]; also toff from tcnt ----------
__global__ void k_scan(const int* __restrict__ deg, int* __restrict__ off,
                       const int* __restrict__ tcnt, int* __restrict__ toff,
                       int N, int E) {
  __shared__ int wsum[16];
  __shared__ int base_s;
  int tid = threadIdx.x;          // 0..1023
  int lane = tid & 63, w = tid >> 6;
  if (tid == 0) {
    base_s = 0;
    toff[0] = 0;
    for (int t = 0; t < T; ++t) toff[t + 1] = toff[t] + ((tcnt[t] + NB - 1) / NB) * NB;
  }
  __syncthreads();
  for (int start = 0; start < N; start += 1024) {
    int i = start + tid;
    int v = (i < N) ? deg[i] : 0;
    int x = v;
#pragma unroll
    for (int o = 1; o < 64; o <<= 1) {
      int y = __shfl_up(x, o);
      if (lane >= o) x += y;
    }
    if (lane == 63) wsum[w] = x;
    __syncthreads();
    if (w == 0 && lane < 16) {
      int s = wsum[lane];
#pragma unroll
      for (int o = 1; o < 16; o <<= 1) {
        int y = __shfl_up(s, o);
        if (lane >= o) s += y;
      }
      wsum[lane] = s;
    }
    __syncthreads();
    int waveoff = (w > 0) ? wsum[w - 1] : 0;
    if (i < N) off[i] = base_s + waveoff + x - v;
    __syncthreads();
    if (tid == 0) base_s += wsum[15];
    __syncthreads();
  }
  if (tid == 0) off[N] = E;
}

// ---------- scatter: edges -> CSR src values; nodes -> type buckets ----------
__global__ void k_scatter(const int* __restrict__ dst, const int* __restrict__ src,
                          const int* __restrict__ ntype,
                          const int* __restrict__ off, const int* __restrict__ toff,
                          int* __restrict__ cursor, int* __restrict__ tcur,
                          int* __restrict__ esrc, int* __restrict__ pnid, int N, int E) {
  int i = blockIdx.x * blockDim.x + threadIdx.x;
  if (i < E) {
    int d = dst[i];
    int pos = atomicAdd(cursor + d, 1);
    esrc[off[d] + pos] = src[i];
  }
  int t = (i < N) ? ntype[i] : -1;
  int lane = threadIdx.x & 63;
#pragma unroll
  for (int tt = 0; tt < T; ++tt) {
    unsigned long long mask = __ballot(t == tt);
    int cnt = __popcll(mask);
    if (cnt == 0) continue;
    int leader = __ffsll((long long)mask) - 1;
    int base = 0;
    if (lane == leader) base = atomicAdd(tcur + tt, cnt);
    base = __shfl(base, leader);
    if (t == tt) {
      int rank = __popcll(mask & ((1ull << lane) - 1ull));
      pnid[toff[tt] + base + rank] = i;
    }
  }
}

// ---------- MFMA typed projection: 16 nodes x 128 out, bf16 in, fp32 acc.
//            blockIdx.y: 0=k, 1=q(->qt), 2=v(->mt). 256 thr = 4 waves, each
//            wave owns 32 output cols (2 col-tiles of 16).
//            A-frag: lane l elem i = A[l&15][(l>>4)*8+i]  (row-major)
//            B-frag: lane l elem i = B[(l>>4)*8+i][l&15]  (Wt col-major [c][k])
//            D: col = lane&15, row = (lane>>4)*4+reg  [verified r10/r14] ----------
__global__ void __launch_bounds__(256)
k_proj_m(const unsigned short* __restrict__ xb, const int* __restrict__ pnid,
         const int* __restrict__ ntype, const unsigned short* __restrict__ Wt,
         const float* __restrict__ ra_, const float* __restrict__ rm_,
         const float* __restrict__ rp,
         unsigned int* __restrict__ kmpk, float* __restrict__ oqt) {
  int b = blockIdx.x, which = blockIdx.y;
  int tid = threadIdx.x;
  int w = tid >> 6, l = tid & 63;
  __shared__ int nid_s[NB];
  if (tid < NB) nid_s[tid] = pnid[b * NB + tid];
  __syncthreads();
  int tfirst = -1;
#pragma unroll
  for (int nn = 0; nn < NB; ++nn) if (tfirst < 0 && nid_s[nn] >= 0) tfirst = ntype[nid_s[nn]];
  if (tfirst < 0) return;  // fully-padded block

  int arow = l & 15, kg = l >> 4;
  int anid = nid_s[arow];
  if (anid < 0) anid = 0;  // clamp: garbage rows never written back
  const unsigned short* abase = xb + (size_t)anid * D + kg * 8;
  const unsigned short* wbase = Wt + ((size_t)which * T + tfirst) * (D * D);
  int col0 = w * 32 + (l & 15);
  const unsigned short* b0 = wbase + (size_t)col0 * D + kg * 8;
  const unsigned short* b1 = b0 + (size_t)16 * D;
  f32x4 acc0 = {0.f, 0.f, 0.f, 0.f}, acc1 = {0.f, 0.f, 0.f, 0.f};
#pragma unroll
  for (int ks = 0; ks < 4; ++ks) {
    bf16x8 af = *(const bf16x8*)(abase + ks * 32);
    bf16x8 bf0 = *(const bf16x8*)(b0 + ks * 32);
    bf16x8 bf1 = *(const bf16x8*)(b1 + ks * 32);
    acc0 = __builtin_amdgcn_mfma_f32_16x16x32_bf16(af, bf0, acc0, 0, 0, 0);
    acc1 = __builtin_amdgcn_mfma_f32_16x16x32_bf16(af, bf1, acc1, 0, 0, 0);
  }

  int o = l & 15, kg4 = (l >> 4) * 4, gbase = l & 48;
  unsigned short* kb = (unsigned short*)kmpk;
  if (which == 0) {  // k -> low bf16 half
#pragma unroll
    for (int ct = 0; ct < 2; ++ct) {
      f32x4 acc = ct ? acc1 : acc0;
      int col = w * 32 + ct * 16 + o;
#pragma unroll
      for (int r = 0; r < 4; ++r) {
        int nid = nid_s[kg4 + r];
        if (nid >= 0) kb[((size_t)nid * D + col) * 2] = f2bf(acc[r]);
      }
    }
  } else if (which == 1) {  // q -> qt (rel_att transform + rel_pri/4 scale)
#pragma unroll
    for (int ct = 0; ct < 2; ++ct) {
      f32x4 acc = ct ? acc1 : acc0;
      int h = 2 * w + ct;
      int col = h * 16 + o;
      float raz[16];
#pragma unroll
      for (int z = 0; z < 16; ++z) raz[z] = ra_[h * 256 + o * 16 + z];
      float rph = rp[h] * 0.25f;
#pragma unroll
      for (int r = 0; r < 4; ++r) {
        float s = 0.f;
#pragma unroll
        for (int z = 0; z < 16; ++z) s += raz[z] * __shfl(acc[r], gbase | z);
        int nid = nid_s[kg4 + r];
        if (nid >= 0) oqt[(size_t)nid * D + col] = s * rph;
      }
    }
  } else {  // v -> mt (rel_msg transform) -> high bf16 half
#pragma unroll
    for (int ct = 0; ct < 2; ++ct) {
      f32x4 acc = ct ? acc1 : acc0;
      int h = 2 * w + ct;
      int col = h * 16 + o;
      float rmz[16];
#pragma unroll
      for (int z = 0; z < 16; ++z) rmz[z] = rm_[h * 256 + z * 16 + o];
#pragma unroll
      for (int r = 0; r < 4; ++r) {
        float s = 0.f;
#pragma unroll
        for (int z = 0; z < 16; ++z) s += rmz[z] * __shfl(acc[r], gbase | z);
        int nid = nid_s[kg4 + r];
        if (nid >= 0) kb[((size_t)nid * D + col) * 2 + 1] = f2bf(s);
      }
    }
  }
}

// ---------- per-node softmax aggregation, no max-shift (|a| << 1, exp safe),
//            4-way unrolled, fully pipelined accumulation ----------
__global__ void k_agg(const int* __restrict__ esrc, const int* __restrict__ off,
                      const unsigned int* __restrict__ kmpk,
                      const float* __restrict__ qt,
                      float* __restrict__ hagg, int N) {
  int n = blockIdx.x;
  int j = threadIdx.x;  // 0..127
  float qv = qt[(size_t)n * D + j];
  int i0 = off[n], i1 = off[n + 1];
  float ssum = 0.f, acc = 0.f;
  int i = i0;
  for (; i + 4 <= i1; i += 4) {
    int s0 = esrc[i], s1 = esrc[i + 1], s2 = esrc[i + 2], s3 = esrc[i + 3];
    unsigned p0 = kmpk[(size_t)s0 * D + j];
    unsigned p1 = kmpk[(size_t)s1 * D + j];
    unsigned p2 = kmpk[(size_t)s2 * D + j];
    unsigned p3 = kmpk[(size_t)s3 * D + j];
    float kv0 = __uint_as_float(p0 << 16), mv0 = __uint_as_float(p0 & 0xffff0000u);
    float kv1 = __uint_as_float(p1 << 16), mv1 = __uint_as_float(p1 & 0xffff0000u);
    float kv2 = __uint_as_float(p2 << 16), mv2 = __uint_as_float(p2 & 0xffff0000u);
    float kv3 = __uint_as_float(p3 << 16), mv3 = __uint_as_float(p3 & 0xffff0000u);
    float a0 = kv0 * qv, a1 = kv1 * qv, a2 = kv2 * qv, a3 = kv3 * qv;
#pragma unroll
    for (int o = 8; o >= 1; o >>= 1) {
      a0 += __shfl_xor(a0, o);
      a1 += __shfl_xor(a1, o);
      a2 += __shfl_xor(a2, o);
      a3 += __shfl_xor(a3, o);
    }
    float w0 = __expf(a0), w1 = __expf(a1), w2 = __expf(a2), w3 = __expf(a3);
    ssum += (w0 + w1) + (w2 + w3);
    acc += (w0 * mv0 + w1 * mv1) + (w2 * mv2 + w3 * mv3);
  }
  for (; i < i1; ++i) {
    int sn = esrc[i];
    unsigned p = kmpk[(size_t)sn * D + j];
    float kv = __uint_as_float(p << 16), mv = __uint_as_float(p & 0xffff0000u);
    float a = kv * qv;
#pragma unroll
    for (int o = 8; o >= 1; o >>= 1) a += __shfl_xor(a, o);
    float wgt = __expf(a);
    ssum += wgt;
    acc += wgt * mv;
  }
  hagg[(size_t)n * D + j] = (ssum > 0.f) ? acc / ssum : 0.f;
}

// ---------- fp32 Wa GEMM, 16 nodes/block, 256 thr (2 col-groups x 8 nodes),
//            unroll-4 pipeline + x prefetch; skip/LN/residual/FiLM epilogue ----------
__global__ void __launch_bounds__(256)
k_out(const float* __restrict__ hagg, const int* __restrict__ pnid,
      const int* __restrict__ ntype, const float* __restrict__ Wa,
      const float* __restrict__ x, const float* __restrict__ skip,
      const float* __restrict__ ln_g, const float* __restrict__ ln_b,
      const float* __restrict__ gb, float* __restrict__ out) {
  int b = blockIdx.x, tid = threadIdx.x;
  int j = tid & 127, g = tid >> 7;  // g in {0,1}: nodes g*8 .. g*8+7
  __shared__ __align__(16) float hs[NBO][D];
  __shared__ int nid_s[NBO];
  __shared__ float red[4][8][2];  // [wave][local nn][s1,s2]
  if (tid < NBO) nid_s[tid] = pnid[b * NBO + tid];
  __syncthreads();
  for (int idx = tid; idx < NBO * D; idx += 256) {
    int nn = idx >> 7, col = idx & 127;
    int nid = nid_s[nn];
    hs[nn][col] = (nid >= 0) ? hagg[(size_t)nid * D + col] : 0.f;
  }
  __syncthreads();
  int tfirst = -1;
#pragma unroll
  for (int nn = 0; nn < NBO; ++nn) if (tfirst < 0 && nid_s[nn] >= 0) tfirst = ntype[nid_s[nn]];
  if (tfirst < 0) return;
  // prefetch epilogue x values: latency hides under the GEMM below
  float xpre[8];
#pragma unroll
  for (int nn = 0; nn < 8; ++nn) {
    int nid = nid_s[g * 8 + nn];
    xpre[nn] = (nid >= 0) ? x[(size_t)nid * D + j] : 0.f;
  }
  const float* wp = Wa + (size_t)tfirst * (D * D) + j;  // coalesced across j
  float acc[8];
#pragma unroll
  for (int nn = 0; nn < 8; ++nn) acc[nn] = 0.f;
#pragma unroll 4
  for (int d = 0; d < D; d += 4) {
    float w0 = wp[(size_t)d * D];
    float w1 = wp[(size_t)(d + 1) * D];
    float w2 = wp[(size_t)(d + 2) * D];
    float w3 = wp[(size_t)(d + 3) * D];
#pragma unroll
    for (int nn = 0; nn < 8; ++nn) {
      float4 h4 = *(const float4*)(&hs[g * 8 + nn][d]);  // ds_read_b128
      acc[nn] = fmaf(h4.x, w0, acc[nn]);
      acc[nn] = fmaf(h4.y, w1, acc[nn]);
      acc[nn] = fmaf(h4.z, w2, acc[nn]);
      acc[nn] = fmaf(h4.w, w3, acc[nn]);
    }
  }
  float alpha = 1.f / (1.f + __expf(-skip[tfirst]));
  int w = tid >> 6;  // 0..3
  float hv[8];
#pragma unroll
  for (int nn = 0; nn < 8; ++nn) {
    int nid = nid_s[g * 8 + nn];
    hv[nn] = (nid >= 0) ? (acc[nn] * alpha + xpre[nn] * (1.f - alpha)) : 0.f;
    float s1 = hv[nn], s2 = hv[nn] * hv[nn];
#pragma unroll
    for (int o = 1; o < 64; o <<= 1) {
      s1 += __shfl_xor(s1, o);
      s2 += __shfl_xor(s2, o);
    }
    if ((tid & 63) == 0) { red[w][nn][0] = s1; red[w][nn][1] = s2; }
  }
  __syncthreads();
  float gj = ln_g[j], bj = ln_b[j], gmj = gb[j], gbj = gb[D + j];
#pragma unroll
  for (int nn = 0; nn < 8; ++nn) {
    int nid = nid_s[g * 8 + nn];
    if (nid < 0) continue;
    float mu = (red[2 * g][nn][0] + red[2 * g + 1][nn][0]) * (1.f / D);
    float m2 = (red[2 * g][nn][1] + red[2 * g + 1][nn][1]) * (1.f / D);
    float var = m2 - mu * mu;
    float y = (hv[nn] - mu) * rsqrtf(var + 1e-5f) * gj + bj + xpre[nn];
    out[(size_t)nid * D + j] = gmj * y + gbj;
  }
}

extern "C" void kernel_launch(void* const* d_in, const int* in_sizes, int n_in,
                              void* d_out, int out_size, void* d_ws, size_t ws_size,
                              hipStream_t stream) {
  const float* x       = (const float*)d_in[0];
  const float* gc      = (const float*)d_in[1];
  const float* Wk      = (const float*)d_in[2];
  const float* Wq      = (const float*)d_in[3];
  const float* Wv      = (const float*)d_in[4];
  const float* rel_att = (const float*)d_in[5];
  const float* rel_msg = (const float*)d_in[6];
  const float* rel_pri = (const float*)d_in[7];
  const float* Wa      = (const float*)d_in[8];
  const float* skip    = (const float*)d_in[9];
  const float* ln_g    = (const float*)d_in[10];
  const float* ln_b    = (const float*)d_in[11];
  const float* fw      = (const float*)d_in[12];
  const float* fb      = (const float*)d_in[13];
  const int* ntype     = (const int*)d_in[14];
  const int* src       = (const int*)d_in[15];
  const int* dst       = (const int*)d_in[16];
  float* out = (float*)d_out;

  int N = in_sizes[0] / D;
  int C = in_sizes[1];
  int E = in_sizes[15];

  int gridP = (N + NB - 1) / NB + T;  // upper bound on padded 16-node tiles
  int P = gridP * NB;                 // padded node-list size
  int gridO = P / NBO;                // 16-node tiles

  float* ws = (float*)d_ws;
  size_t nD = (size_t)N * D;
  float* wqt   = ws;                                 // N*128 fp32 qt (scaled)
  float* whagg = wqt + nD;                           // N*128 fp32 h_agg
  float* wgb   = whagg + nD;                         // 256 gamma|beta
  unsigned int*   kmpk = (unsigned int*)(wgb + 256); // N*128 packed {k,mt} bf16
  unsigned short* xb   = (unsigned short*)(kmpk + nD);  // N*128 bf16 x
  unsigned short* Wt   = xb + nD;                    // 3*3*128*128 bf16 col-major
  int* deg    = (int*)(Wt + 9 * D * D);  // N  (zeroed: deg,cursor,tcnt,tcur)
  int* cursor = deg + N;                 // N
  int* tcnt   = cursor + N;              // T
  int* tcur   = tcnt + T;                // T
  int* off    = tcur + T;                // N+1
  int* toff   = off + N + 1;             // T+1
  int* esrc   = toff + T + 1;            // E  (CSR-ordered src values)
  int* pnid   = esrc + E;                // P  (memset 0xFF -> -1)

  (void)hipMemsetAsync(deg, 0, (size_t)(2 * N + 2 * T) * sizeof(int), stream);
  (void)hipMemsetAsync(pnid, 0xFF, (size_t)P * sizeof(int), stream);

  int mNE = (E > N) ? E : N;
  int n8 = (int)(nD / 8);
  int BE = (mNE + 255) / 256;
  int BX = (n8 + 255) / 256;
  k_prep<<<10 + BE + BX, 256, 0, stream>>>(dst, ntype, deg, tcnt, N, E,
                                           x, xb, n8, Wk, Wq, Wv, Wt,
                                           gc, fw, fb, wgb, C, BE, BX);
  k_scan<<<1, 1024, 0, stream>>>(deg, off, tcnt, toff, N, E);
  k_scatter<<<(mNE + 255) / 256, 256, 0, stream>>>(dst, src, ntype, off, toff,
                                                   cursor, tcur, esrc, pnid, N, E);
  k_proj_m<<<dim3(gridP, 3, 1), 256, 0, stream>>>(xb, pnid, ntype, Wt, rel_att,
                                                  rel_msg, rel_pri, kmpk, wqt);
  k_agg<<<N, D, 0, stream>>>(esrc, off, kmpk, wqt, whagg, N);
  k_out<<<gridO, 256, 0, stream>>>(whagg, pnid, ntype, Wa, x, skip, ln_g, ln_b,
                                   wgb, out);
}

// Round 19
// 196.176 us; speedup vs baseline: 1.2821x; 1.0200x over previous
//
#include <hip/hip_runtime.h>
#include <hip/hip_bf16.h>

constexpr int D  = 128;
constexpr int H  = 8;
constexpr int DH = 16;
constexpr int NB  = 16;  // nodes per MFMA tile / type-bucket alignment
constexpr int NBO = 16;  // nodes per k_out tile
constexpr int T  = 3;

typedef __attribute__((ext_vector_type(8))) short bf16x8;
typedef __attribute__((ext_vector_type(4))) float f32x4;

__device__ inline unsigned short f2bf(float f) {  // fp32 -> bf16 bits (RNE)
  unsigned u = __float_as_uint(f);
  unsigned r = u + 0x7fffu + ((u >> 16) & 1u);
  return (unsigned short)(r >> 16);
}

// ---------- fused prep. Block roles (latency-bound tails FIRST):
//   blk 0: FiLM;  [1,10): cast_w;  [10,10+BE): edge count+hist;
//   [10+BE, 10+BE+BX): cast x ----------
__global__ void k_prep(const int* __restrict__ dst, const int* __restrict__ ntype,
                       int* __restrict__ deg, int* __restrict__ tcnt, int N, int E,
                       const float* __restrict__ x, unsigned short* __restrict__ xb,
                       int n8,
                       const float* __restrict__ Wk, const float* __restrict__ Wq,
                       const float* __restrict__ Wv, unsigned short* __restrict__ Wt,
                       const float* __restrict__ gc, const float* __restrict__ fw,
                       const float* __restrict__ fb, float* __restrict__ gb, int C,
                       int BE, int BX) {
  int blk = blockIdx.x, tid = threadIdx.x;
  if (blk == 0) {  // FiLM: gb[0:128]=gamma, gb[128:256]=beta (256 threads)
    float a0 = 0.f, a1 = 0.f, a2 = 0.f, a3 = 0.f;
    int c = 0;
    for (; c + 4 <= C; c += 4) {
      a0 += gc[c] * fw[c * 256 + tid];
      a1 += gc[c + 1] * fw[(c + 1) * 256 + tid];
      a2 += gc[c + 2] * fw[(c + 2) * 256 + tid];
      a3 += gc[c + 3] * fw[(c + 3) * 256 + tid];
    }
    float acc = fb[tid] + (a0 + a1) + (a2 + a3);
    for (; c < C; ++c) acc += gc[c] * fw[c * 256 + tid];
    gb[tid] = acc;
    return;
  }
  if (blk < 10) {  // cast+transpose Wk/Wq/Wv -> bf16 [col][k]; coalesced WRITES
    int b2 = blk - 1;
    int m = b2 / T, t = b2 % T;
    const float* W = (m == 0 ? Wk : m == 1 ? Wq : Wv) + (size_t)t * (D * D);
    unsigned short* o = Wt + ((size_t)m * T + t) * (D * D);
    for (int idx = tid; idx < D * D; idx += 256) {
      int c = idx >> 7, d = idx & 127;         // consecutive tid -> consecutive d
      o[(size_t)c * D + d] = f2bf(W[(size_t)d * D + c]);  // write coalesced
    }
    return;
  }
  if (blk < 10 + BE) {  // edge in-degree count + node type histogram
    int i = (blk - 10) * 256 + tid;
    if (i < E) atomicAdd(deg + dst[i], 1);
    int t = (i < N) ? ntype[i] : -1;
    int lane = tid & 63;
#pragma unroll
    for (int tt = 0; tt < T; ++tt) {
      unsigned long long mask = __ballot(t == tt);
      int cnt = __popcll(mask);
      if (cnt > 0 && lane == (__ffsll((long long)mask) - 1))
        atomicAdd(tcnt + tt, cnt);
    }
    return;
  }
  // cast x -> bf16, 8 elems/thread
  int i = (blk - 10 - BE) * 256 + tid;
  if (i >= n8) return;
  const float4* p = (const float4*)(x + (size_t)i * 8);
  float4 a = p[0], b = p[1];
  ushort4 o0 = {f2bf(a.x), f2bf(a.y), f2bf(a.z), f2bf(a.w)};
  ushort4 o1 = {f2bf(b.x), f2bf(b.y), f2bf(b.z), f2bf(b.w)};
  ushort4* q = (ushort4*)(xb + (size_t)i * 8);
  q[0] = o0;
  q[1] = o1;
}

// ---------- exclusive prefix sum over deg -> off[0..N]; also toff from tcnt ----------
__global__ void k_scan(const int* __restrict__ deg, int* __restrict__ off,
                       const int* __restrict__ tcnt, int* __restrict__ toff,
                       int N, int E) {
  __shared__ int wsum[16];
  __shared__ int base_s;
  int tid = threadIdx.x;          // 0..1023
  int lane = tid & 63, w = tid >> 6;
  if (tid == 0) {
    base_s = 0;
    toff[0] = 0;
    for (int t = 0; t < T; ++t) toff[t + 1] = toff[t] + ((tcnt[t] + NB - 1) / NB) * NB;
  }
  __syncthreads();
  for (int start = 0; start < N; start += 1024) {
    int i = start + tid;
    int v = (i < N) ? deg[i] : 0;
    int x = v;
#pragma unroll
    for (int o = 1; o < 64; o <<= 1) {
      int y = __shfl_up(x, o);
      if (lane >= o) x += y;
    }
    if (lane == 63) wsum[w] = x;
    __syncthreads();
    if (w == 0 && lane < 16) {
      int s = wsum[lane];
#pragma unroll
      for (int o = 1; o < 16; o <<= 1) {
        int y = __shfl_up(s, o);
        if (lane >= o) s += y;
      }
      wsum[lane] = s;
    }
    __syncthreads();
    int waveoff = (w > 0) ? wsum[w - 1] : 0;
    if (i < N) off[i] = base_s + waveoff + x - v;
    __syncthreads();
    if (tid == 0) base_s += wsum[15];
    __syncthreads();
  }
  if (tid == 0) off[N] = E;
}

// ---------- scatter: edges -> CSR src values; nodes -> type buckets ----------
__global__ void k_scatter(const int* __restrict__ dst, const int* __restrict__ src,
                          const int* __restrict__ ntype,
                          const int* __restrict__ off, const int* __restrict__ toff,
                          int* __restrict__ cursor, int* __restrict__ tcur,
                          int* __restrict__ esrc, int* __restrict__ pnid, int N, int E) {
  int i = blockIdx.x * blockDim.x + threadIdx.x;
  if (i < E) {
    int d = dst[i];
    int pos = atomicAdd(cursor + d, 1);
    esrc[off[d] + pos] = src[i];
  }
  int t = (i < N) ? ntype[i] : -1;
  int lane = threadIdx.x & 63;
#pragma unroll
  for (int tt = 0; tt < T; ++tt) {
    unsigned long long mask = __ballot(t == tt);
    int cnt = __popcll(mask);
    if (cnt == 0) continue;
    int leader = __ffsll((long long)mask) - 1;
    int base = 0;
    if (lane == leader) base = atomicAdd(tcur + tt, cnt);
    base = __shfl(base, leader);
    if (t == tt) {
      int rank = __popcll(mask & ((1ull << lane) - 1ull));
      pnid[toff[tt] + base + rank] = i;
    }
  }
}

// ---------- MFMA typed projection: 16 nodes x 128 out, bf16 in, fp32 acc.
//            blockIdx.y: 0=k, 1=q(->qt), 2=v(->mt). 256 thr = 4 waves, each
//            wave owns 32 output cols (2 col-tiles of 16).
//            A-frag: lane l elem i = A[l&15][(l>>4)*8+i]  (row-major)
//            B-frag: lane l elem i = B[(l>>4)*8+i][l&15]  (Wt col-major [c][k])
//            D: col = lane&15, row = (lane>>4)*4+reg  [verified r10/r14] ----------
__global__ void __launch_bounds__(256)
k_proj_m(const unsigned short* __restrict__ xb, const int* __restrict__ pnid,
         const int* __restrict__ ntype, const unsigned short* __restrict__ Wt,
         const float* __restrict__ ra_, const float* __restrict__ rm_,
         const float* __restrict__ rp,
         unsigned int* __restrict__ kmpk, float* __restrict__ oqt) {
  int b = blockIdx.x, which = blockIdx.y;
  int tid = threadIdx.x;
  int w = tid >> 6, l = tid & 63;
  __shared__ int nid_s[NB];
  if (tid < NB) nid_s[tid] = pnid[b * NB + tid];
  __syncthreads();
  int tfirst = -1;
#pragma unroll
  for (int nn = 0; nn < NB; ++nn) if (tfirst < 0 && nid_s[nn] >= 0) tfirst = ntype[nid_s[nn]];
  if (tfirst < 0) return;  // fully-padded block

  int arow = l & 15, kg = l >> 4;
  int anid = nid_s[arow];
  if (anid < 0) anid = 0;  // clamp: garbage rows never written back
  const unsigned short* abase = xb + (size_t)anid * D + kg * 8;
  const unsigned short* wbase = Wt + ((size_t)which * T + tfirst) * (D * D);
  int col0 = w * 32 + (l & 15);
  const unsigned short* b0 = wbase + (size_t)col0 * D + kg * 8;
  const unsigned short* b1 = b0 + (size_t)16 * D;
  f32x4 acc0 = {0.f, 0.f, 0.f, 0.f}, acc1 = {0.f, 0.f, 0.f, 0.f};
#pragma unroll
  for (int ks = 0; ks < 4; ++ks) {
    bf16x8 af = *(const bf16x8*)(abase + ks * 32);
    bf16x8 bf0 = *(const bf16x8*)(b0 + ks * 32);
    bf16x8 bf1 = *(const bf16x8*)(b1 + ks * 32);
    acc0 = __builtin_amdgcn_mfma_f32_16x16x32_bf16(af, bf0, acc0, 0, 0, 0);
    acc1 = __builtin_amdgcn_mfma_f32_16x16x32_bf16(af, bf1, acc1, 0, 0, 0);
  }

  int o = l & 15, kg4 = (l >> 4) * 4, gbase = l & 48;
  unsigned short* kb = (unsigned short*)kmpk;
  if (which == 0) {  // k -> low bf16 half
#pragma unroll
    for (int ct = 0; ct < 2; ++ct) {
      f32x4 acc = ct ? acc1 : acc0;
      int col = w * 32 + ct * 16 + o;
#pragma unroll
      for (int r = 0; r < 4; ++r) {
        int nid = nid_s[kg4 + r];
        if (nid >= 0) kb[((size_t)nid * D + col) * 2] = f2bf(acc[r]);
      }
    }
  } else if (which == 1) {  // q -> qt (rel_att transform + rel_pri/4 scale)
#pragma unroll
    for (int ct = 0; ct < 2; ++ct) {
      f32x4 acc = ct ? acc1 : acc0;
      int h = 2 * w + ct;
      int col = h * 16 + o;
      float raz[16];
#pragma unroll
      for (int z = 0; z < 16; ++z) raz[z] = ra_[h * 256 + o * 16 + z];
      float rph = rp[h] * 0.25f;
#pragma unroll
      for (int r = 0; r < 4; ++r) {
        float s = 0.f;
#pragma unroll
        for (int z = 0; z < 16; ++z) s += raz[z] * __shfl(acc[r], gbase | z);
        int nid = nid_s[kg4 + r];
        if (nid >= 0) oqt[(size_t)nid * D + col] = s * rph;
      }
    }
  } else {  // v -> mt (rel_msg transform) -> high bf16 half
#pragma unroll
    for (int ct = 0; ct < 2; ++ct) {
      f32x4 acc = ct ? acc1 : acc0;
      int h = 2 * w + ct;
      int col = h * 16 + o;
      float rmz[16];
#pragma unroll
      for (int z = 0; z < 16; ++z) rmz[z] = rm_[h * 256 + z * 16 + o];
#pragma unroll
      for (int r = 0; r < 4; ++r) {
        float s = 0.f;
#pragma unroll
        for (int z = 0; z < 16; ++z) s += rmz[z] * __shfl(acc[r], gbase | z);
        int nid = nid_s[kg4 + r];
        if (nid >= 0) kb[((size_t)nid * D + col) * 2 + 1] = f2bf(s);
      }
    }
  }
}

// ---------- per-node softmax aggregation, no max-shift (|a| << 1, exp safe),
//            4-way unrolled, fully pipelined accumulation ----------
__global__ void k_agg(const int* __restrict__ esrc, const int* __restrict__ off,
                      const unsigned int* __restrict__ kmpk,
                      const float* __restrict__ qt,
                      float* __restrict__ hagg, int N) {
  int n = blockIdx.x;
  int j = threadIdx.x;  // 0..127
  float qv = qt[(size_t)n * D + j];
  int i0 = off[n], i1 = off[n + 1];
  float ssum = 0.f, acc = 0.f;
  int i = i0;
  for (; i + 4 <= i1; i += 4) {
    int s0 = esrc[i], s1 = esrc[i + 1], s2 = esrc[i + 2], s3 = esrc[i + 3];
    unsigned p0 = kmpk[(size_t)s0 * D + j];
    unsigned p1 = kmpk[(size_t)s1 * D + j];
    unsigned p2 = kmpk[(size_t)s2 * D + j];
    unsigned p3 = kmpk[(size_t)s3 * D + j];
    float kv0 = __uint_as_float(p0 << 16), mv0 = __uint_as_float(p0 & 0xffff0000u);
    float kv1 = __uint_as_float(p1 << 16), mv1 = __uint_as_float(p1 & 0xffff0000u);
    float kv2 = __uint_as_float(p2 << 16), mv2 = __uint_as_float(p2 & 0xffff0000u);
    float kv3 = __uint_as_float(p3 << 16), mv3 = __uint_as_float(p3 & 0xffff0000u);
    float a0 = kv0 * qv, a1 = kv1 * qv, a2 = kv2 * qv, a3 = kv3 * qv;
#pragma unroll
    for (int o = 8; o >= 1; o >>= 1) {
      a0 += __shfl_xor(a0, o);
      a1 += __shfl_xor(a1, o);
      a2 += __shfl_xor(a2, o);
      a3 += __shfl_xor(a3, o);
    }
    float w0 = __expf(a0), w1 = __expf(a1), w2 = __expf(a2), w3 = __expf(a3);
    ssum += (w0 + w1) + (w2 + w3);
    acc += (w0 * mv0 + w1 * mv1) + (w2 * mv2 + w3 * mv3);
  }
  for (; i < i1; ++i) {
    int sn = esrc[i];
    unsigned p = kmpk[(size_t)sn * D + j];
    float kv = __uint_as_float(p << 16), mv = __uint_as_float(p & 0xffff0000u);
    float a = kv * qv;
#pragma unroll
    for (int o = 8; o >= 1; o >>= 1) a += __shfl_xor(a, o);
    float wgt = __expf(a);
    ssum += wgt;
    acc += wgt * mv;
  }
  hagg[(size_t)n * D + j] = (ssum > 0.f) ? acc / ssum : 0.f;
}

// ---------- fp32 Wa GEMM, 16 nodes/block, 512 thr (4 node-groups x 4 nodes),
//            unroll-4 pipeline + x prefetch; skip/LN/residual/FiLM epilogue ----------
__global__ void __launch_bounds__(512)
k_out(const float* __restrict__ hagg, const int* __restrict__ pnid,
      const int* __restrict__ ntype, const float* __restrict__ Wa,
      const float* __restrict__ x, const float* __restrict__ skip,
      const float* __restrict__ ln_g, const float* __restrict__ ln_b,
      const float* __restrict__ gb, float* __restrict__ out) {
  int b = blockIdx.x, tid = threadIdx.x;
  int j = tid & 127, g = tid >> 7;  // g in {0..3}: nodes g*4 .. g*4+3
  __shared__ __align__(16) float hs[NBO][D];
  __shared__ int nid_s[NBO];
  __shared__ float red[8][4][2];  // [wave][local nn][s1,s2]
  if (tid < NBO) nid_s[tid] = pnid[b * NBO + tid];
  __syncthreads();
  for (int idx = tid; idx < NBO * D; idx += 512) {
    int nn = idx >> 7, col = idx & 127;
    int nid = nid_s[nn];
    hs[nn][col] = (nid >= 0) ? hagg[(size_t)nid * D + col] : 0.f;
  }
  __syncthreads();
  int tfirst = -1;
#pragma unroll
  for (int nn = 0; nn < NBO; ++nn) if (tfirst < 0 && nid_s[nn] >= 0) tfirst = ntype[nid_s[nn]];
  if (tfirst < 0) return;
  // prefetch epilogue x values: latency hides under the GEMM below
  float xpre[4];
#pragma unroll
  for (int nn = 0; nn < 4; ++nn) {
    int nid = nid_s[g * 4 + nn];
    xpre[nn] = (nid >= 0) ? x[(size_t)nid * D + j] : 0.f;
  }
  const float* wp = Wa + (size_t)tfirst * (D * D) + j;  // coalesced across j
  float acc[4];
#pragma unroll
  for (int nn = 0; nn < 4; ++nn) acc[nn] = 0.f;
#pragma unroll 4
  for (int d = 0; d < D; d += 4) {
    float w0 = wp[(size_t)d * D];
    float w1 = wp[(size_t)(d + 1) * D];
    float w2 = wp[(size_t)(d + 2) * D];
    float w3 = wp[(size_t)(d + 3) * D];
#pragma unroll
    for (int nn = 0; nn < 4; ++nn) {
      float4 h4 = *(const float4*)(&hs[g * 4 + nn][d]);  // ds_read_b128
      acc[nn] = fmaf(h4.x, w0, acc[nn]);
      acc[nn] = fmaf(h4.y, w1, acc[nn]);
      acc[nn] = fmaf(h4.z, w2, acc[nn]);
      acc[nn] = fmaf(h4.w, w3, acc[nn]);
    }
  }
  float alpha = 1.f / (1.f + __expf(-skip[tfirst]));
  int w = tid >> 6;  // 0..7
  float hv[4];
#pragma unroll
  for (int nn = 0; nn < 4; ++nn) {
    int nid = nid_s[g * 4 + nn];
    hv[nn] = (nid >= 0) ? (acc[nn] * alpha + xpre[nn] * (1.f - alpha)) : 0.f;
    float s1 = hv[nn], s2 = hv[nn] * hv[nn];
#pragma unroll
    for (int o = 1; o < 64; o <<= 1) {
      s1 += __shfl_xor(s1, o);
      s2 += __shfl_xor(s2, o);
    }
    if ((tid & 63) == 0) { red[w][nn][0] = s1; red[w][nn][1] = s2; }
  }
  __syncthreads();
  float gj = ln_g[j], bj = ln_b[j], gmj = gb[j], gbj = gb[D + j];
#pragma unroll
  for (int nn = 0; nn < 4; ++nn) {
    int nid = nid_s[g * 4 + nn];
    if (nid < 0) continue;
    float mu = (red[2 * g][nn][0] + red[2 * g + 1][nn][0]) * (1.f / D);
    float m2 = (red[2 * g][nn][1] + red[2 * g + 1][nn][1]) * (1.f / D);
    float var = m2 - mu * mu;
    float y = (hv[nn] - mu) * rsqrtf(var + 1e-5f) * gj + bj + xpre[nn];
    out[(size_t)nid * D + j] = gmj * y + gbj;
  }
}

extern "C" void kernel_launch(void* const* d_in, const int* in_sizes, int n_in,
                              void* d_out, int out_size, void* d_ws, size_t ws_size,
                              hipStream_t stream) {
  const float* x       = (const float*)d_in[0];
  const float* gc      = (const float*)d_in[1];
  const float* Wk      = (const float*)d_in[2];
  const float* Wq      = (const float*)d_in[3];
  const float* Wv      = (const float*)d_in[4];
  const float* rel_att = (const float*)d_in[5];
  const float* rel_msg = (const float*)d_in[6];
  const float* rel_pri = (const float*)d_in[7];
  const float* Wa      = (const float*)d_in[8];
  const float* skip    = (const float*)d_in[9];
  const float* ln_g    = (const float*)d_in[10];
  const float* ln_b    = (const float*)d_in[11];
  const float* fw      = (const float*)d_in[12];
  const float* fb      = (const float*)d_in[13];
  const int* ntype     = (const int*)d_in[14];
  const int* src       = (const int*)d_in[15];
  const int* dst       = (const int*)d_in[16];
  float* out = (float*)d_out;

  int N = in_sizes[0] / D;
  int C = in_sizes[1];
  int E = in_sizes[15];

  int gridP = (N + NB - 1) / NB + T;  // upper bound on padded 16-node tiles
  int P = gridP * NB;                 // padded node-list size
  int gridO = P / NBO;                // 16-node tiles

  float* ws = (float*)d_ws;
  size_t nD = (size_t)N * D;
  float* wqt   = ws;                                 // N*128 fp32 qt (scaled)
  float* whagg = wqt + nD;                           // N*128 fp32 h_agg
  float* wgb   = whagg + nD;                         // 256 gamma|beta
  unsigned int*   kmpk = (unsigned int*)(wgb + 256); // N*128 packed {k,mt} bf16
  unsigned short* xb   = (unsigned short*)(kmpk + nD);  // N*128 bf16 x
  unsigned short* Wt   = xb + nD;                    // 3*3*128*128 bf16 col-major
  int* deg    = (int*)(Wt + 9 * D * D);  // N  (zeroed: deg,cursor,tcnt,tcur)
  int* cursor = deg + N;                 // N
  int* tcnt   = cursor + N;              // T
  int* tcur   = tcnt + T;                // T
  int* off    = tcur + T;                // N+1
  int* toff   = off + N + 1;             // T+1
  int* esrc   = toff + T + 1;            // E  (CSR-ordered src values)
  int* pnid   = esrc + E;                // P  (memset 0xFF -> -1)

  (void)hipMemsetAsync(deg, 0, (size_t)(2 * N + 2 * T) * sizeof(int), stream);
  (void)hipMemsetAsync(pnid, 0xFF, (size_t)P * sizeof(int), stream);

  int mNE = (E > N) ? E : N;
  int n8 = (int)(nD / 8);
  int BE = (mNE + 255) / 256;
  int BX = (n8 + 255) / 256;
  k_prep<<<10 + BE + BX, 256, 0, stream>>>(dst, ntype, deg, tcnt, N, E,
                                           x, xb, n8, Wk, Wq, Wv, Wt,
                                           gc, fw, fb, wgb, C, BE, BX);
  k_scan<<<1, 1024, 0, stream>>>(deg, off, tcnt, toff, N, E);
  k_scatter<<<(mNE + 255) / 256, 256, 0, stream>>>(dst, src, ntype, off, toff,
                                                   cursor, tcur, esrc, pnid, N, E);
  k_proj_m<<<dim3(gridP, 3, 1), 256, 0, stream>>>(xb, pnid, ntype, Wt, rel_att,
                                                  rel_msg, rel_pri, kmpk, wqt);
  k_agg<<<N, D, 0, stream>>>(esrc, off, kmpk, wqt, whagg, N);
  k_out<<<gridO, 512, 0, stream>>>(whagg, pnid, ntype, Wa, x, skip, ln_g, ln_b,
                                   wgb, out);
}